// Round 17
// baseline (633.756 us; speedup 1.0000x reference)
//
#include <hip/hip_runtime.h>
#include <string.h>

typedef _Float16 f16x8 __attribute__((ext_vector_type(8)));
typedef _Float16 f16x4 __attribute__((ext_vector_type(4)));
typedef __fp16   hf2   __attribute__((ext_vector_type(2)));
typedef float    f32x4 __attribute__((ext_vector_type(4)));

// Generic 2-level row addressing: addr(r) = (r>>sh)*hi + (r&msk)*lo   (in elements)
struct Addr { long hi; long lo; int sh; int msk; };

__device__ __forceinline__ long raddr(const Addr a, int r) {
  return ((long)(r >> a.sh)) * a.hi + ((long)(r & a.msk)) * a.lo;
}

struct GP {
  int M, N, K1, K2;
  const float* A1; Addr a1;    // K-segment 1 rows (f32)
  const float* A2; Addr a2;    // K-segment 2 rows (optional, K2>0)
  const _Float16* Bh; int ldbh;// f16 [n][k] pre-transposed B operand
  const float* scale;          // optional: alpha *= *scale
  float alpha;
  const float* E1; Addr e1; float beta;   // C1 = alpha*acc + beta*E1
  float* C1; Addr c1;
  _Float16* C1h; int ldh;      // optional f16 transposed shadow of C1 value
  float* C2; Addr c2;          // C2 = alpha*acc + E2
  const float* E2; Addr e2;
  const float* fin;            // 256 partials: sscale=1/sqrt(sum); A*=sscale, alpha*=sscale
  float* fout;                 // per-block sum of squares of written values
};

struct GPB { GP g[10]; };

__device__ __forceinline__ f16x4 pk4s(f32x4 v, float ss) {
  hf2 lo = __builtin_amdgcn_cvt_pkrtz(v[0] * ss, v[1] * ss);
  hf2 hi = __builtin_amdgcn_cvt_pkrtz(v[2] * ss, v[3] * ss);
  f16x4 h;
  h[0] = (_Float16)lo[0]; h[1] = (_Float16)lo[1];
  h[2] = (_Float16)hi[0]; h[3] = (_Float16)hi[1];
  return h;
}

// Tiled GEMM, f32 A / f16 B -> f16 LDS -> f32 accum. 4 waves (2x2), single
// LDS buffer. DEEP=true: 3 register sets, loads issue 2 tiles ahead of
// consumption (latency-bound small-grid serial dispatches).
// Requires (K1+K2) % 64 == 0, N % BN == 0.
template<int BM, bool DEEP>
__device__ __forceinline__ void gemm_body(const GP& p) {
  constexpr int BN = BM;
  constexpr int WT = BM / 2;
  constexpr int FM = WT / 16;
  constexpr int NAQ = BM / 32;                   // A f32x4 loads per thread
  constexpr int NBH = BN / 64;                   // B f16x8 loads per thread
  __shared__ _Float16 As[BM * 40];
  __shared__ _Float16 Bs[BN * 40];
  __shared__ float red[256];
  const int tid = threadIdx.x;
  const int nbn = (p.N + BN - 1) / BN;
  const int nbm = (p.M + BM - 1) / BM;
  if ((int)blockIdx.x >= nbm * nbn) return;
  int bm, bn;
  {
    const int bid = blockIdx.x;
    if ((nbm & 7) == 0) {   // stripe-XCD swizzle
      bm = (bid & 7) + ((bid >> 3) / nbn) * 8;
      bn = (bid >> 3) % nbn;
    } else {
      bm = bid / nbn; bn = bid - bm * nbn;
    }
  }
  const int m0 = bm * BM, n0 = bn * BN;

  float sscale = 1.0f;
  if (p.fin) {
    red[tid] = p.fin[tid];
    __syncthreads();
    for (int st = 128; st > 0; st >>= 1) {
      if (tid < st) red[tid] += red[tid + st];
      __syncthreads();
    }
    sscale = 1.0f / sqrtf(red[0]);
    __syncthreads();
  }
  float alpha = p.alpha;
  if (p.scale) alpha *= p.scale[0];
  if (p.fin) alpha *= sscale;

  const int w = tid >> 6, l = tid & 63;
  const int wm = w >> 1, wn = w & 1;
  const int lr = l & 15, lg = l >> 4;

  f32x4 acc[FM][FM];
  #pragma unroll
  for (int m = 0; m < FM; ++m)
    #pragma unroll
    for (int n = 0; n < FM; ++n) acc[m][n] = {0.f, 0.f, 0.f, 0.f};

  const int Kt = p.K1 + p.K2;

  f32x4 aR0[NAQ], aR1[NAQ];
  f16x8 b2R0[NBH], b2R1[NBH];

  auto loadT = [&](int k0, f32x4* aR, f16x8* b2R) {
    const float* Ab; Addr aa; long kl;
    if (k0 < p.K1) { Ab = p.A1; aa = p.a1; kl = k0; }
    else           { Ab = p.A2; aa = p.a2; kl = (long)k0 - p.K1; }
    #pragma unroll
    for (int i = 0; i < NAQ; ++i) {
      const int gq = tid + (i << 8);
      const int ar_ = gq >> 3, kq = gq & 7;
      f32x4 v = {0.f, 0.f, 0.f, 0.f};
      if (m0 + ar_ < p.M) v = *(const f32x4*)(Ab + raddr(aa, m0 + ar_) + kl + kq * 4);
      aR[i] = v;
    }
    #pragma unroll
    for (int i = 0; i < NBH; ++i) {
      const int row = (tid >> 2) + i * 64;
      b2R[i] = *(const f16x8*)(p.Bh + (long)(n0 + row) * p.ldbh + k0 + (tid & 3) * 8);
    }
  };
  auto storeLDS = [&](const f32x4* aR, const f16x8* b2R) {
    #pragma unroll
    for (int i = 0; i < NAQ; ++i) {
      const int gq = tid + (i << 8);
      const int ar_ = gq >> 3, kq = gq & 7;
      *(f16x4*)&As[ar_ * 40 + kq * 4] = pk4s(aR[i], sscale);
    }
    #pragma unroll
    for (int i = 0; i < NBH; ++i) {
      const int row = (tid >> 2) + i * 64;
      *(f16x8*)&Bs[row * 40 + (tid & 3) * 8] = b2R[i];
    }
  };
  auto compute = [&]() {
    f16x8 a[FM], b[FM];
    #pragma unroll
    for (int m = 0; m < FM; ++m)
      a[m] = *(const f16x8*)&As[(wm * WT + m * 16 + lr) * 40 + lg * 8];
    #pragma unroll
    for (int n = 0; n < FM; ++n)
      b[n] = *(const f16x8*)&Bs[(wn * WT + n * 16 + lr) * 40 + lg * 8];
    #pragma unroll
    for (int m = 0; m < FM; ++m)
      #pragma unroll
      for (int n = 0; n < FM; ++n)
        acc[m][n] = __builtin_amdgcn_mfma_f32_16x16x32_f16(a[m], b[n], acc[m][n], 0, 0, 0);
  };

  if constexpr (DEEP) {
    f32x4 aRC[NAQ];
    f16x8 bRC[NBH];
    loadT(0, aR0, b2R0);
    if (Kt > 32) loadT(32, aR1, b2R1);
    for (int k0 = 0; k0 < Kt; k0 += 32) {
      if (k0 + 64 < Kt) loadT(k0 + 64, aRC, bRC);   // 2 tiles ahead
      storeLDS(aR0, b2R0);
      __syncthreads();
      compute();
      __syncthreads();
      #pragma unroll
      for (int i = 0; i < NAQ; ++i) aR0[i] = aR1[i];
      #pragma unroll
      for (int i = 0; i < NBH; ++i) b2R0[i] = b2R1[i];
      #pragma unroll
      for (int i = 0; i < NAQ; ++i) aR1[i] = aRC[i];
      #pragma unroll
      for (int i = 0; i < NBH; ++i) b2R1[i] = bRC[i];
    }
  } else {
    loadT(0, aR0, b2R0);
    for (int k0 = 0; k0 < Kt; k0 += 64) {
      storeLDS(aR0, b2R0);
      __syncthreads();
      loadT(k0 + 32, aR1, b2R1);   // prefetch overlaps compute
      compute();
      __syncthreads();
      storeLDS(aR1, b2R1);
      __syncthreads();
      if (k0 + 64 < Kt) loadT(k0 + 64, aR0, b2R0);
      compute();
      __syncthreads();
    }
  }

  float ssq = 0.0f;
  #pragma unroll
  for (int m = 0; m < FM; ++m) {
    #pragma unroll
    for (int n = 0; n < FM; ++n) {
      #pragma unroll
      for (int rr = 0; rr < 4; ++rr) {
        const int ro = m0 + wm * WT + m * 16 + lg * 4 + rr;
        const int no = n0 + wn * WT + n * 16 + lr;
        if (ro < p.M) {
          float val = alpha * acc[m][n][rr];
          float o1 = val;
          if (p.E1) o1 += p.beta * p.E1[raddr(p.e1, ro) + no];
          if (p.C1) p.C1[raddr(p.c1, ro) + no] = o1;
          if (p.C1h) p.C1h[(long)no * p.ldh + ro] = (_Float16)o1;
          if (p.C2) p.C2[raddr(p.c2, ro) + no] = val + p.E2[raddr(p.e2, ro) + no];
          ssq += val * val;
        }
      }
    }
  }
  if (p.fout) {
    __syncthreads();
    red[tid] = ssq;
    __syncthreads();
    for (int st = 128; st > 0; st >>= 1) {
      if (tid < st) red[tid] += red[tid + st];
      __syncthreads();
    }
    if (tid == 0) p.fout[blockIdx.x] = red[0];
  }
}

__global__ __launch_bounds__(256) void gemm_u64(GPB pb)  { gemm_body<64, true>(pb.g[blockIdx.y]); }
__global__ __launch_bounds__(256) void gemm_u128(GPB pb) { gemm_body<128, false>(pb.g[blockIdx.y]); }

// Fused prep before squaring chain: Krt, KrH, St, X0, X0H, Za-init,
// K11u/K12u (unscaled f32 transposes), K21uH (unscaled f16), zerosH
__global__ void prep1_k(const float* S, const float* Kr, const float* st0,
                        float* Krt, _Float16* KrH, float* St, float* Xa,
                        _Float16* XaH, float* Za,
                        float* K11u, float* K12u, _Float16* K21uH,
                        _Float16* zerosH) {
  const int op = blockIdx.y;
  const int tx = threadIdx.x, ty = threadIdx.y;
  const int lid = ty * 32 + tx;
  if (op == 4) {            // XaH = 2I - S (direct f16)
    if (blockIdx.x >= 256) return;
    const int base = (blockIdx.x * 256 + lid) * 4;
    #pragma unroll
    for (int q = 0; q < 4; ++q) {
      const int e = base + q;
      const int i = e >> 9, j = e & 511;
      XaH[e] = (_Float16)(((i == j) ? 2.0f : 0.0f) - S[(long)i * 512 + j]);
    }
    return;
  }
  if (op == 5) {            // Za[b][0] = st0[b]
    if (blockIdx.x >= 32) return;
    const int idx = blockIdx.x * 256 + lid;
    const int b = idx >> 9, j = idx & 511;
    Za[(long)b * 262144 + j] = st0[idx];
    return;
  }
  if (op == 8) {            // K21uH[n][k] = Kr[512+n][k] (f16, unscaled)
    if (blockIdx.x >= 256) return;
    const int base = (blockIdx.x * 256 + lid) * 4;
    #pragma unroll
    for (int q = 0; q < 4; ++q) {
      const int e = base + q;
      const int n = e >> 9, k = e & 511;
      K21uH[e] = (_Float16)Kr[(long)(512 + n) * 1024 + k];
    }
    return;
  }
  if (op == 9) {            // zerosH = 0 (32768 f16)
    if (blockIdx.x >= 32) return;
    const int base = (blockIdx.x * 256 + lid);
    *(f16x4*)&zerosH[base * 4] = f16x4{0, 0, 0, 0};
    return;
  }
  __shared__ float t[32][33];
  if (op <= 1) {            // 1024x1024 transposes of Kr
    if (blockIdx.x >= 1024) return;
    const int bx = blockIdx.x & 31, by = blockIdx.x >> 5;
    const long I0 = (long)bx * 32, J0 = (long)by * 32;
    #pragma unroll
    for (int k = 0; k < 4; ++k)
      t[ty * 4 + k][tx] = Kr[(J0 + ty * 4 + k) * 1024 + I0 + tx];
    __syncthreads();
    #pragma unroll
    for (int k = 0; k < 4; ++k) {
      const long i = I0 + ty * 4 + k, j = J0 + tx;
      if (op == 0) Krt[i * 1024 + j] = t[tx][ty * 4 + k];
      else         KrH[i * 1024 + j] = (_Float16)t[tx][ty * 4 + k];
    }
  } else {                  // 512x512 transposes: op2 St, op3 X0, op6 K11u, op7 K12u
    if (blockIdx.x >= 256) return;
    const int bx = blockIdx.x & 15, by = blockIdx.x >> 4;
    const long I0 = (long)bx * 32, J0 = (long)by * 32;
    const float* src;
    long ld, coff;
    if (op == 6) { src = Kr; ld = 1024; coff = 0; }
    else if (op == 7) { src = Kr; ld = 1024; coff = 512; }
    else { src = S; ld = 512; coff = 0; }
    #pragma unroll
    for (int k = 0; k < 4; ++k)
      t[ty * 4 + k][tx] = src[(J0 + ty * 4 + k) * ld + coff + I0 + tx];
    __syncthreads();
    #pragma unroll
    for (int k = 0; k < 4; ++k) {
      const long i = I0 + ty * 4 + k, j = J0 + tx;
      if (op == 2) St[i * 512 + j] = t[tx][ty * 4 + k];
      else if (op == 3) Xa[i * 512 + j] = ((i == j) ? 2.0f : 0.0f) - t[tx][ty * 4 + k];
      else if (op == 6) K11u[i * 512 + j] = t[tx][ty * 4 + k];
      else K12u[i * 512 + j] = t[tx][ty * 4 + k];
    }
  }
}

// Post-chain rescale (scalar folded in: every block reduces P itself).
// op0 ABstH; op1 StackH; op2 CtDtH; op3 APf2(f32); op4 Stack4H cols 512..2560
__global__ void prep2_k(const float* Kr, const float* P, const float* lg,
                        _Float16* ABstH, _Float16* StackH,
                        const _Float16* BtuH, _Float16* CtDtH, float* APf2,
                        _Float16* Stack4H, const float* BtAtU) {
  __shared__ float red[256];
  __shared__ float sv[9];
  const int lid = threadIdx.y * 32 + threadIdx.x;
  for (int k = 0; k < 9; ++k) {
    red[lid] = P[k * 256 + lid];
    __syncthreads();
    for (int st = 128; st > 0; st >>= 1) {
      if (lid < st) red[lid] += red[lid + st];
      __syncthreads();
    }
    if (lid == 0) sv[k] = red[0];
    __syncthreads();
  }
  double lnl = 0.0, wgt = 1.0;
  for (int k = 0; k < 9; ++k) {
    lnl += wgt * log(sqrt((double)sv[k]));
    if (k < 8) wgt *= 0.5;
  }
  double sigma = exp(0.5 * lnl);
  if (sigma < 1e-5) sigma = 1e-5;
  const float invk = (float)(1.0 / (sigma + 0.002));
  const float gma  = (float)exp((double)lg[0]);
  const float gik  = gma * invk;
  const float ik2  = invk * invk;
  const float ik2g = ik2 * gma;
  const float ik3g = ik2 * invk * gma;
  const float ik4g = ik2 * ik2 * gma;

  const int op = blockIdx.y;
  if (op == 0) {            // ABstH [512][1024]: AtH*=invk ; BtH = gik*BtuH
    if (blockIdx.x >= 512) return;
    const int base = (blockIdx.x * 256 + lid) * 4;
    #pragma unroll
    for (int q = 0; q < 4; ++q) {
      const int e = base + q;
      const int n = e >> 10, c = e & 1023;
      if (c < 512) ABstH[e] = (_Float16)((float)ABstH[e] * invk);
      else ABstH[e] = (_Float16)(gik * (float)BtuH[(long)n * 512 + (c - 512)]);
    }
  } else if (op == 1) {     // StackH [512][1536]: At2*=ik2 ; BtAt*=ik2g ; Bt=gik*BtuH
    if (blockIdx.x >= 768) return;
    const int base = (blockIdx.x * 256 + lid) * 4;
    #pragma unroll
    for (int q = 0; q < 4; ++q) {
      const int e = base + q;
      const int n = e / 1536, c = e - n * 1536;
      float v;
      if (c < 512) v = (float)StackH[e] * ik2;
      else if (c < 1024) v = (float)StackH[e] * ik2g;
      else v = gik * (float)BtuH[(long)n * 512 + (c - 1024)];
      StackH[e] = (_Float16)v;
    }
  } else if (op == 2) {     // CtDtH [512][1024]: Ct*=invk ; Dt = gik*K22
    if (blockIdx.x >= 512) return;
    const int base = (blockIdx.x * 256 + lid) * 4;
    #pragma unroll
    for (int q = 0; q < 4; ++q) {
      const int e = base + q;
      const int n = e >> 10, c = e & 1023;
      if (c < 512) CtDtH[e] = (_Float16)((float)CtDtH[e] * invk);
      else CtDtH[e] = (_Float16)(gik * Kr[(long)(512 + n) * 1024 + 512 + (c - 512)]);
    }
  } else if (op == 3) {     // APf2 f32 *= ik2
    if (blockIdx.x >= 256) return;
    const int base = (blockIdx.x * 256 + lid) * 4;
    #pragma unroll
    for (int q = 0; q < 4; ++q) APf2[base + q] *= ik2;
  } else {                  // Stack4H cols 512..2560: [BtAt3|BtAt2|BtAt|Bt]
    if (blockIdx.x >= 1024) return;
    const int base = (blockIdx.x * 256 + lid) * 4;
    #pragma unroll
    for (int q = 0; q < 4; ++q) {
      const int e = base + q;           // e in [0, 512*2048)
      const int n = e >> 11, c = e & 2047;
      _Float16* dst = &Stack4H[(long)n * 2560 + 512 + c];
      float v;
      if (c < 512) v = (float)*dst * ik4g;                         // BtAt3 in-place
      else if (c < 1024) v = (float)*dst * ik3g;                   // BtAt2 in-place
      else if (c < 1536) v = ik2g * BtAtU[(long)(c - 1024) * 512 + n];  // BtAt
      else v = gik * (float)BtuH[(long)n * 512 + (c - 1536)];      // Bt
      *dst = (_Float16)v;
    }
  }
}

static inline Addr lin(long stride) {
  Addr a; a.hi = 0; a.lo = stride; a.sh = 20; a.msk = 0xFFFFF; return a;
}
static inline Addr two(int sh, long hi, int msk, long lo) {
  Addr a; a.hi = hi; a.lo = lo; a.sh = sh; a.msk = msk; return a;
}
static inline GP gp0() {
  GP p; memset(&p, 0, sizeof(p)); p.alpha = 1.0f; p.beta = 1.0f; return p;
}

extern "C" void kernel_launch(void* const* d_in, const int* in_sizes, int n_in,
                              void* d_out, int out_size, void* d_ws, size_t ws_size,
                              hipStream_t stream) {
  (void)in_sizes; (void)n_in; (void)out_size; (void)ws_size;
  const float* u    = (const float*)d_in[0];  // [16][2048][512]
  const float* st0  = (const float*)d_in[1];  // [16][512]
  const float* S    = (const float*)d_in[2];  // [512][512]
  const float* Kr   = (const float*)d_in[3];  // [1024][1024]
  const float* lgam = (const float*)d_in[4];  // [1]

  float* outp   = (float*)d_out;                       // [16][2048][512]
  float* states = outp + (long)16 * 2048 * 512;        // [16][2049][512]
  float* ws = (float*)d_ws;

  const int NSQ = 8;
  float* P  = ws + 64;            // (NSQ+1)*256 frobenius partials
  float* base = ws + 3456;

  // ws layout (float offsets from ws):
  float* Krt = base;                  // 1024^2 f32 (dead after d1); MbH overlays
  _Float16* MbH = (_Float16*)base;
  float* Ma  = base + 1048576;
  float* Mb  = base + 2097152;        // ends ws+3149184
  _Float16* CtDtH  = (_Float16*)(ws + 3149248);   // [512][1024] (ends 3411392)
  _Float16* MaH    = (_Float16*)(ws + 3419584);   // [1024][1024] (ends 3943872)
  _Float16* StackH = (_Float16*)(ws + 3943872);   // [512][1536] (ends 4337088)
  _Float16* zerosH = (_Float16*)(ws + 4337088);   // [512][64] zeros (64 KiB)

  // outp region (dead before final GEMM writes)
  float* Za  = outp;                  // [16][512][512] KS ping
  float* Zb  = outp + 4194304;        // [16][512][512] KS pong
  float* APb = outp + 8388608;        // At^j f32, j=2..8
  float* Tb  = outp + 10223616;       // T(k) f32 + unscaled temps
  float* K11u  = Tb;                  // dead after k=6; T1 f32 reuses after KS0
  float* K12u  = Tb + 262144;         // dead after k=7
  float* AtU   = Tb + 524288;         // dead after k=8
  float* BtU   = Tb + 786432;         // dead after k=8
  float* BtAtU = Tb;                  // k=8 rider C1 (K11u dead); dead after prep2
  _Float16* h16   = (_Float16*)(outp + 12320768);
  _Float16* ABstH = h16;                       // [512][1024]: AtH | BtH
  _Float16* APH_  = h16 + 524288;              // At^j shadows j=3..8 (6 slots)
  _Float16* TmH_  = h16 + 2097152;             // T(k) shadows k=1..2
  _Float16* XaH   = h16 + 4194304;
  _Float16* XbH   = XaH + 262144;
  _Float16* YnH   = XbH + 262144;
  _Float16* WH    = YnH + 262144;
  _Float16* K21uH = WH + 262144;
  _Float16* KrH   = K21uH + 262144;            // [1024][1024] (ends h16+6553600)
  _Float16* BtuH  = h16 + 6553600;             // [512][512] (ends h16+6815744)
  float* St = outp + 15728640;                 // f32 Newton buffers (live <= k7)
  float* Xa = outp + 15990784;                 // dead after k5
  float* Xb = outp + 16252928;                 // dead after k5 (XbH carries on)
  float* Yn = outp + 16515072;                 // dead after k5
  // Stack4H overlays Xa/Xb/Yn (written first at stack-finish, after k8)
  _Float16* Stack4H = (_Float16*)(outp + 15990784);  // [512][2560] (ends 16646144 f32)

  auto APf = [&](int j) -> float* {
    return APb + (long)(j - 2) * 262144;       // j=2..8
  };
  // f16 shadow of At^j: j=1 ABstH, j=2 StackH, j=4 Stack4H, else APH_
  auto APHp = [&](int j) -> const _Float16* {
    if (j == 1) return ABstH;
    if (j == 2) return StackH;
    if (j == 4) return Stack4H;
    return APH_ + (long)(j - 3) * 262144;
  };
  auto APHl = [&](int j) {
    return (j == 1) ? 1024 : ((j == 2) ? 1536 : ((j == 4) ? 2560 : 512));
  };
  auto Tmf = [&](int k) -> float* { return (k == 0) ? APf(8) : Tb + (long)(k - 1) * 262144; };
  auto TmH = [&](int k) -> _Float16* {
    return (k == 0) ? (_Float16*)APHp(8) : TmH_ + (long)(k - 1) * 262144;
  };

  auto launch64 = [&](const GP* gs, int nb) {
    GPB pb; memset(&pb, 0, sizeof(pb));
    int mx = 0;
    for (int i = 0; i < nb; ++i) {
      pb.g[i] = gs[i];
      int b = ((gs[i].M + 63) / 64) * ((gs[i].N + 63) / 64);
      if (b > mx) mx = b;
    }
    gemm_u64<<<dim3(mx, nb), dim3(256), 0, stream>>>(pb);
  };
  auto launch128 = [&](const GP* gs, int nb) {
    GPB pb; memset(&pb, 0, sizeof(pb));
    int mx = 0;
    for (int i = 0; i < nb; ++i) {
      pb.g[i] = gs[i];
      int b = ((gs[i].M + 127) / 128) * ((gs[i].N + 127) / 128);
      if (b > mx) mx = b;
    }
    gemm_u128<<<dim3(mx, nb), dim3(256), 0, stream>>>(pb);
  };

  // 512^3 helper: C f32 (optional) + f16 transposed shadow (optional)
  auto mmh = [&](const float* A, const _Float16* Bh, int ldbh,
                 float* C, _Float16* Ch, int ldh) {
    GP g = gp0(); g.M = 512; g.N = 512; g.K1 = 512;
    g.A1 = A; g.a1 = lin(512);
    g.Bh = Bh; g.ldbh = ldbh;
    g.C1 = C; g.c1 = lin(512);
    g.C1h = Ch; g.ldh = ldh;
    return g;
  };
  auto cpGP = [&](const float* src, Addr sa, float* dst, Addr da, int M) {
    GP g = gp0(); g.M = M; g.N = 512; g.K1 = 64;
    g.A1 = src; g.a1 = sa;
    g.Bh = zerosH; g.ldbh = 64;
    g.E1 = src; g.e1 = sa; g.beta = 1.0f;
    g.C1 = dst; g.c1 = da;
    return g;
  };

  prep1_k<<<dim3(1024, 10), dim3(32, 8), 0, stream>>>(S, Kr, st0, Krt, KrH,
                                                      St, Xa, XaH, Za,
                                                      K11u, K12u, K21uH, zerosH);

  // ---- phase A: squaring chain; Newton rides k=1..5; unscaled ABCD rides
  //      k=6 (W~, Ct~), k=7 (At~, Bt~), k=8 (At~^2, Bt~At~) ----
  {
    GP gs[2];
    gs[0] = gp0();
    gs[0].M = 1024; gs[0].N = 1024; gs[0].K1 = 1024;
    gs[0].A1 = Krt; gs[0].a1 = lin(1024);
    gs[0].Bh = KrH; gs[0].ldbh = 1024;
    gs[0].C1 = Ma; gs[0].c1 = lin(1024);
    gs[0].C1h = MaH; gs[0].ldh = 1024;     // M0 symmetric -> shadow == M0
    gs[0].fout = P;
    gs[1] = mmh(St, XaH, 512, Yn, YnH, 512);   // Newton 1a
    launch64(gs, 2);
  }
  for (int k = 1; k <= NSQ; ++k) {
    const bool odd = (k % 2 == 1);
    float* cur = odd ? Ma : Mb;
    float* nxt = odd ? Mb : Ma;
    _Float16* curH = odd ? MaH : MbH;
    _Float16* nxtH = odd ? MbH : MaH;
    GP gs[3];
    gs[0] = gp0();
    gs[0].M = 1024; gs[0].N = 1024; gs[0].K1 = 1024;
    gs[0].A1 = cur; gs[0].a1 = lin(1024);
    gs[0].Bh = curH; gs[0].ldbh = 1024;    // symmetric f16 shadow as B
    gs[0].C1 = nxt; gs[0].c1 = lin(1024);
    gs[0].C1h = nxtH; gs[0].ldh = 1024;
    gs[0].fin = P + (long)(k - 1) * 256;   // A *= sscale, alpha *= sscale
    gs[0].fout = P + (long)k * 256;
    int nb = 1;
    if (k <= 5) {
      if (odd) {           // Newton b-step: X' = 2X - X@Yn
        float* cx = (k == 1 || k == 5) ? Xa : Xb;
        float* nx = (k == 1 || k == 5) ? Xb : Xa;
        _Float16* nxH = (k == 1 || k == 5) ? XbH : XaH;
        GP h = mmh(cx, YnH, 512, nx, nxH, 512);
        h.alpha = -1.0f; h.E1 = cx; h.e1 = lin(512); h.beta = 2.0f;
        gs[nb++] = h;
      } else {             // Newton a-step: Yn = St @ X
        _Float16* cxH = (k == 2) ? XbH : XaH;
        gs[nb++] = mmh(St, cxH, 512, Yn, YnH, 512);
      }
    } else if (k == 6) {
      gs[nb++] = mmh(K11u, XbH, 512, nullptr, WH, 512);      // W~ = K11^T@SinvT
      gs[nb++] = mmh(St, K21uH, 512, nullptr, CtDtH, 1024);  // Ct~ (unscaled)
    } else if (k == 7) {
      gs[nb++] = mmh(St, WH, 512, AtU, ABstH, 1024);         // At~ + At~H
      gs[nb++] = mmh(K12u, XbH, 512, BtU, BtuH, 512);        // Bt~ + Bt~H
    } else {
      gs[nb++] = mmh(AtU, ABstH, 1024, APf(2), StackH, 1536);  // At~^2
      gs[nb++] = mmh(BtU, ABstH, 1024, BtAtU, StackH + 512, 1536); // Bt~At~ (+f32)
    }
    launch64(gs, nb);
  }

  // ---- stack-finish (unscaled): Bt~At~^2, Bt~At~^3 into Stack4H ----
  {
    GP gs[2];
    gs[0] = mmh(BtAtU, ABstH, 1024, nullptr, Stack4H + 1024, 2560);  // Bt~At~^2
    gs[1] = mmh(BtAtU, StackH, 1536, nullptr, Stack4H + 512, 2560);  // Bt~At~^3
    launch64(gs, 2);
  }
  prep2_k<<<dim3(1024, 5), dim3(32, 8), 0, stream>>>(Kr, P, lgam, ABstH, StackH,
                                                     BtuH, CtDtH, APf(2),
                                                     Stack4H, BtAtU);

  // Addressing constants (L=8, 256 chunks/batch)
  const Addr A_u8   = two(8, 1048576, 255, 4096);
  const Addr A_s8   = two(8, 1049088, 255, 4096);
  const Addr A_z    = two(8, 262144, 255, 512);
  const Addr A_srow = two(11, 1049088, 2047, 512);

  // ---- pass1 radix-4: 2 serial steps (j=4, j=8) ----
  // l_4 = u_{0..3}@[BtAt3;BtAt2;BtAt;Bt]   (Stack4H rows 512..2560)
  // l_8 = l_4@At4 + u_{4..7}@[...]          (Stack4H full)
  {
    GP gs[3];
    gs[0] = gp0();
    gs[0].M = 4096; gs[0].N = 512;
    gs[0].K1 = 2048; gs[0].A1 = u; gs[0].a1 = A_u8;   // u rows 8c+0..3 contiguous
    gs[0].Bh = Stack4H + 512; gs[0].ldbh = 2560;
    gs[0].C1 = states + (long)4 * 512; gs[0].c1 = A_s8;
    gs[1] = mmh(APf(2), ABstH, 1024, nullptr, APH_ + 0, 512);        // At^3
    gs[2] = mmh(APf(2), StackH, 1536, APf(4), Stack4H, 2560);        // At^4
    launch64(gs, 3);
  }
  {
    GP gs[5];
    gs[0] = gp0();
    gs[0].M = 4096; gs[0].N = 512;
    gs[0].K1 = 512; gs[0].A1 = states + (long)4 * 512; gs[0].a1 = A_s8;
    gs[0].K2 = 2048; gs[0].A2 = u + (long)4 * 512; gs[0].a2 = A_u8;
    gs[0].Bh = Stack4H; gs[0].ldbh = 2560;
    gs[0].C1 = Za + 512; gs[0].c1 = A_z;
    gs[1] = mmh(APf(4), ABstH, 1024, nullptr, APH_ + 2 * 262144, 512);  // At^5
    gs[2] = mmh(APf(4), StackH, 1536, nullptr, APH_ + 3 * 262144, 512); // At^6
    gs[3] = mmh(APf(4), APH_ + 0, 512, nullptr, APH_ + 4 * 262144, 512);// At^7
    gs[4] = mmh(APf(4), Stack4H, 2560, APf(8), APH_ + 5 * 262144, 512); // At^8=Q
    launch64(gs, 5);
  }

  // ---- Truncated Kogge-Stone (3 rounds, window 8); fills + T-chain ride ----
  for (int k = 0; k <= 2; ++k) {
    const int s = 1 << k;
    float* Zs = (k % 2 == 0) ? Za : Zb;
    float* Zd = (k % 2 == 0) ? Zb : Za;
    GP gs[8];
    int nb = 0;
    GP m = gp0();
    m.M = 4096; m.N = 512; m.K1 = 512;
    m.A1 = Zs; m.a1 = A_z;
    m.Bh = TmH(k); m.ldbh = 512;
    m.E1 = Zs + (long)s * 512; m.e1 = A_z; m.beta = 1.0f;
    m.C1 = Zd + (long)s * 512; m.c1 = A_z;
    gs[nb++] = m;
    const Addr lowA = two(k, 262144, s - 1, 512);
    gs[nb++] = cpGP(Zs, lowA, Zd, lowA, 16 * s);
    if (k == 0) {
      // level-1 fills: l_1, l_2, l_5, l_6
      {
        GP g = gp0(); g.M = 4096; g.N = 512;
        g.K1 = 512; g.A1 = u; g.a1 = A_u8;
        g.Bh = ABstH + 512; g.ldbh = 1024;          // l_1 = u_0@Bt
        g.C1 = states + (long)1 * 512; g.c1 = A_s8;
        gs[nb++] = g;
      }
      {
        GP g = gp0(); g.M = 4096; g.N = 512;
        g.K1 = 1024; g.A1 = u; g.a1 = A_u8;
        g.Bh = StackH + 512; g.ldbh = 1536;         // l_2 = u_{0,1}@[BtAt;Bt]
        g.C1 = states + (long)2 * 512; g.c1 = A_s8;
        gs[nb++] = g;
      }
      {
        GP g = gp0(); g.M = 4096; g.N = 512;
        g.K1 = 512; g.A1 = states + (long)4 * 512; g.a1 = A_s8;
        g.K2 = 512; g.A2 = u + (long)4 * 512; g.a2 = A_u8;
        g.Bh = ABstH; g.ldbh = 1024;                // l_5 = l_4@At + u_4@Bt
        g.C1 = states + (long)5 * 512; g.c1 = A_s8;
        gs[nb++] = g;
      }
      {
        GP g = gp0(); g.M = 4096; g.N = 512;
        g.K1 = 512; g.A1 = states + (long)4 * 512; g.a1 = A_s8;
        g.K2 = 1024; g.A2 = u + (long)4 * 512; g.a2 = A_u8;
        g.Bh = StackH; g.ldbh = 1536;               // l_6 = l_4@At2 + u_{4,5}@[BtAt;Bt]
        g.C1 = states + (long)6 * 512; g.c1 = A_s8;
        gs[nb++] = g;
      }
      gs[nb++] = mmh(Tmf(0), TmH(0), 512, Tmf(1), TmH(1), 512);   // T1 = Q^2
    } else if (k == 1) {
      // level-2 fills: l_3, l_7
      {
        GP g = gp0(); g.M = 4096; g.N = 512;
        g.K1 = 512; g.A1 = states + (long)2 * 512; g.a1 = A_s8;
        g.K2 = 512; g.A2 = u + (long)2 * 512; g.a2 = A_u8;
        g.Bh = ABstH; g.ldbh = 1024;                // l_3 = l_2@At + u_2@Bt
        g.C1 = states + (long)3 * 512; g.c1 = A_s8;
        gs[nb++] = g;
      }
      {
        GP g = gp0(); g.M = 4096; g.N = 512;
        g.K1 = 512; g.A1 = states + (long)6 * 512; g.a1 = A_s8;
        g.K2 = 512; g.A2 = u + (long)6 * 512; g.a2 = A_u8;
        g.Bh = ABstH; g.ldbh = 1024;                // l_7 = l_6@At + u_6@Bt
        g.C1 = states + (long)7 * 512; g.c1 = A_s8;
        gs[nb++] = g;
      }
      gs[nb++] = mmh(Tmf(1), TmH(1), 512, nullptr, TmH(2), 512);  // T2 = Q^4
    }
    launch64(gs, nb);
  }
  float* Zf = Zb;   // rounds 0,1,2 end in Zb

  // ---- corrections + states-extreme copies (one dispatch) ----
  {
    GP gs[9];
    for (int j = 1; j <= 7; ++j) {
      GP g = gp0();
      g.M = 4096; g.N = 512; g.K1 = 512;
      g.A1 = Zf; g.a1 = A_z;
      g.Bh = APHp(j); g.ldbh = APHl(j);
      g.C2 = states + (long)j * 512; g.c2 = A_s8;
      g.E2 = states + (long)j * 512; g.e2 = A_s8;
      gs[j - 1] = g;
    }
    gs[7] = cpGP(Zf, A_z, states, A_s8, 4096);
    gs[8] = cpGP(Zf + (long)256 * 512, lin(262144),
                 states + (long)2048 * 512, lin(1049088), 16);
    launch128(gs, 9);
  }

  // ---- output = states[:, :T] @ Ct + u @ Dt ----
  {
    GP g = gp0();
    g.M = 32768; g.N = 512;
    g.K1 = 512; g.A1 = states; g.a1 = A_srow;
    g.K2 = 512; g.A2 = u; g.a2 = lin(512);
    g.Bh = CtDtH; g.ldbh = 1024;
    g.C1 = outp; g.c1 = lin(512);
    launch128(&g, 1);
  }
}

// Round 18
// 597.481 us; speedup vs baseline: 1.0607x; 1.0607x over previous
//
#include <hip/hip_runtime.h>
#include <string.h>

typedef _Float16 f16x8 __attribute__((ext_vector_type(8)));
typedef _Float16 f16x4 __attribute__((ext_vector_type(4)));
typedef __fp16   hf2   __attribute__((ext_vector_type(2)));
typedef float    f32x4 __attribute__((ext_vector_type(4)));

// Generic 2-level row addressing: addr(r) = (r>>sh)*hi + (r&msk)*lo   (in elements)
struct Addr { long hi; long lo; int sh; int msk; };

__device__ __forceinline__ long raddr(const Addr a, int r) {
  return ((long)(r >> a.sh)) * a.hi + ((long)(r & a.msk)) * a.lo;
}

struct GP {
  int M, N, K1, K2;
  const float* A1; Addr a1;    // K-segment 1 rows (f32)
  const float* A2; Addr a2;    // K-segment 2 rows (optional, K2>0)
  const _Float16* Bh; int ldbh;// f16 [n][k] pre-transposed B operand
  const float* scale;          // optional: alpha *= *scale
  float alpha;
  const float* E1; Addr e1; float beta;   // C1 = alpha*acc + beta*E1
  float* C1; Addr c1;
  _Float16* C1h; int ldh;      // optional f16 transposed shadow of C1 value
  float* C2; Addr c2;          // C2 = alpha*acc + E2
  const float* E2; Addr e2;
  const float* fin;            // 256 partials: sscale=1/sqrt(sum); A*=sscale, alpha*=sscale
  float* fout;                 // per-block sum of squares of written values
};

struct GPB { GP g[10]; };

__device__ __forceinline__ f16x4 pk4s(f32x4 v, float ss) {
  hf2 lo = __builtin_amdgcn_cvt_pkrtz(v[0] * ss, v[1] * ss);
  hf2 hi = __builtin_amdgcn_cvt_pkrtz(v[2] * ss, v[3] * ss);
  f16x4 h;
  h[0] = (_Float16)lo[0]; h[1] = (_Float16)lo[1];
  h[2] = (_Float16)hi[0]; h[3] = (_Float16)hi[1];
  return h;
}

// Tiled GEMM, f32 A / f16 B -> f16 LDS -> f32 accum. 4 waves (2x2), single
// LDS buffer. DEEP: 3 register sets, loads issue 2 tiles (~1400cy) ahead of
// consumption — hides HBM/L2 latency on latency-bound dispatches.
// fin: A staged *sscale and alpha *= sscale (squaring-chain normalization).
// Requires (K1+K2) % 64 == 0, N % BN == 0.
template<int BM, bool DEEP>
__device__ __forceinline__ void gemm_body(const GP& p) {
  constexpr int BN = BM;
  constexpr int WT = BM / 2;
  constexpr int FM = WT / 16;
  constexpr int NAQ = BM / 32;                   // A f32x4 loads per thread
  constexpr int NBH = BN / 64;                   // B f16x8 loads per thread
  __shared__ _Float16 As[BM * 40];
  __shared__ _Float16 Bs[BN * 40];
  __shared__ float red[256];
  const int tid = threadIdx.x;
  const int nbn = (p.N + BN - 1) / BN;
  const int nbm = (p.M + BM - 1) / BM;
  if ((int)blockIdx.x >= nbm * nbn) return;
  int bm, bn;
  {
    const int bid = blockIdx.x;
    if ((nbm & 7) == 0) {   // stripe-XCD swizzle
      bm = (bid & 7) + ((bid >> 3) / nbn) * 8;
      bn = (bid >> 3) % nbn;
    } else {
      bm = bid / nbn; bn = bid - bm * nbn;
    }
  }
  const int m0 = bm * BM, n0 = bn * BN;

  float sscale = 1.0f;
  if (p.fin) {
    red[tid] = p.fin[tid];
    __syncthreads();
    for (int st = 128; st > 0; st >>= 1) {
      if (tid < st) red[tid] += red[tid + st];
      __syncthreads();
    }
    sscale = 1.0f / sqrtf(red[0]);
    __syncthreads();
  }
  float alpha = p.alpha;
  if (p.scale) alpha *= p.scale[0];
  if (p.fin) alpha *= sscale;

  const int w = tid >> 6, l = tid & 63;
  const int wm = w >> 1, wn = w & 1;
  const int lr = l & 15, lg = l >> 4;

  f32x4 acc[FM][FM];
  #pragma unroll
  for (int m = 0; m < FM; ++m)
    #pragma unroll
    for (int n = 0; n < FM; ++n) acc[m][n] = {0.f, 0.f, 0.f, 0.f};

  const int Kt = p.K1 + p.K2;

  f32x4 aR0[NAQ], aR1[NAQ];
  f16x8 b2R0[NBH], b2R1[NBH];

  auto loadT = [&](int k0, f32x4* aR, f16x8* b2R) {
    const float* Ab; Addr aa; long kl;
    if (k0 < p.K1) { Ab = p.A1; aa = p.a1; kl = k0; }
    else           { Ab = p.A2; aa = p.a2; kl = (long)k0 - p.K1; }
    #pragma unroll
    for (int i = 0; i < NAQ; ++i) {
      const int gq = tid + (i << 8);
      const int ar_ = gq >> 3, kq = gq & 7;
      f32x4 v = {0.f, 0.f, 0.f, 0.f};
      if (m0 + ar_ < p.M) v = *(const f32x4*)(Ab + raddr(aa, m0 + ar_) + kl + kq * 4);
      aR[i] = v;
    }
    #pragma unroll
    for (int i = 0; i < NBH; ++i) {
      const int row = (tid >> 2) + i * 64;
      b2R[i] = *(const f16x8*)(p.Bh + (long)(n0 + row) * p.ldbh + k0 + (tid & 3) * 8);
    }
  };
  auto storeLDS = [&](const f32x4* aR, const f16x8* b2R) {
    #pragma unroll
    for (int i = 0; i < NAQ; ++i) {
      const int gq = tid + (i << 8);
      const int ar_ = gq >> 3, kq = gq & 7;
      *(f16x4*)&As[ar_ * 40 + kq * 4] = pk4s(aR[i], sscale);
    }
    #pragma unroll
    for (int i = 0; i < NBH; ++i) {
      const int row = (tid >> 2) + i * 64;
      *(f16x8*)&Bs[row * 40 + (tid & 3) * 8] = b2R[i];
    }
  };
  auto compute = [&]() {
    f16x8 a[FM], b[FM];
    #pragma unroll
    for (int m = 0; m < FM; ++m)
      a[m] = *(const f16x8*)&As[(wm * WT + m * 16 + lr) * 40 + lg * 8];
    #pragma unroll
    for (int n = 0; n < FM; ++n)
      b[n] = *(const f16x8*)&Bs[(wn * WT + n * 16 + lr) * 40 + lg * 8];
    #pragma unroll
    for (int m = 0; m < FM; ++m)
      #pragma unroll
      for (int n = 0; n < FM; ++n)
        acc[m][n] = __builtin_amdgcn_mfma_f32_16x16x32_f16(a[m], b[n], acc[m][n], 0, 0, 0);
  };

  if constexpr (DEEP) {
    f32x4 aRC[NAQ];
    f16x8 bRC[NBH];
    loadT(0, aR0, b2R0);
    if (Kt > 32) loadT(32, aR1, b2R1);
    for (int k0 = 0; k0 < Kt; k0 += 32) {
      if (k0 + 64 < Kt) loadT(k0 + 64, aRC, bRC);   // 2 tiles ahead
      storeLDS(aR0, b2R0);
      __syncthreads();
      compute();
      __syncthreads();
      #pragma unroll
      for (int i = 0; i < NAQ; ++i) aR0[i] = aR1[i];
      #pragma unroll
      for (int i = 0; i < NBH; ++i) b2R0[i] = b2R1[i];
      #pragma unroll
      for (int i = 0; i < NAQ; ++i) aR1[i] = aRC[i];
      #pragma unroll
      for (int i = 0; i < NBH; ++i) b2R1[i] = bRC[i];
    }
  } else {
    loadT(0, aR0, b2R0);
    for (int k0 = 0; k0 < Kt; k0 += 64) {
      storeLDS(aR0, b2R0);
      __syncthreads();
      loadT(k0 + 32, aR1, b2R1);   // prefetch overlaps compute
      compute();
      __syncthreads();
      storeLDS(aR1, b2R1);
      __syncthreads();
      if (k0 + 64 < Kt) loadT(k0 + 64, aR0, b2R0);
      compute();
      __syncthreads();
    }
  }

  float ssq = 0.0f;
  #pragma unroll
  for (int m = 0; m < FM; ++m) {
    #pragma unroll
    for (int n = 0; n < FM; ++n) {
      #pragma unroll
      for (int rr = 0; rr < 4; ++rr) {
        const int ro = m0 + wm * WT + m * 16 + lg * 4 + rr;
        const int no = n0 + wn * WT + n * 16 + lr;
        if (ro < p.M) {
          float val = alpha * acc[m][n][rr];
          float o1 = val;
          if (p.E1) o1 += p.beta * p.E1[raddr(p.e1, ro) + no];
          if (p.C1) p.C1[raddr(p.c1, ro) + no] = o1;
          if (p.C1h) p.C1h[(long)no * p.ldh + ro] = (_Float16)o1;
          if (p.C2) p.C2[raddr(p.c2, ro) + no] = val + p.E2[raddr(p.e2, ro) + no];
          ssq += val * val;
        }
      }
    }
  }
  if (p.fout) {
    __syncthreads();
    red[tid] = ssq;
    __syncthreads();
    for (int st = 128; st > 0; st >>= 1) {
      if (tid < st) red[tid] += red[tid + st];
      __syncthreads();
    }
    if (tid == 0) p.fout[blockIdx.x] = red[0];
  }
}

__global__ __launch_bounds__(256) void gemm_u64(GPB pb)  { gemm_body<64, true>(pb.g[blockIdx.y]); }
__global__ __launch_bounds__(256) void gemm_u128(GPB pb) { gemm_body<128, true>(pb.g[blockIdx.y]); }

// Fused prep before squaring chain: Krt, KrH, St, X0, X0H, Za-init,
// K11u/K12u (unscaled f32 transposes), K21uH (unscaled f16), zerosH
__global__ void prep1_k(const float* S, const float* Kr, const float* st0,
                        float* Krt, _Float16* KrH, float* St, float* Xa,
                        _Float16* XaH, float* Za,
                        float* K11u, float* K12u, _Float16* K21uH,
                        _Float16* zerosH) {
  const int op = blockIdx.y;
  const int tx = threadIdx.x, ty = threadIdx.y;
  const int lid = ty * 32 + tx;
  if (op == 4) {            // XaH = 2I - S (direct f16)
    if (blockIdx.x >= 256) return;
    const int base = (blockIdx.x * 256 + lid) * 4;
    #pragma unroll
    for (int q = 0; q < 4; ++q) {
      const int e = base + q;
      const int i = e >> 9, j = e & 511;
      XaH[e] = (_Float16)(((i == j) ? 2.0f : 0.0f) - S[(long)i * 512 + j]);
    }
    return;
  }
  if (op == 5) {            // Za[b][0] = st0[b]
    if (blockIdx.x >= 32) return;
    const int idx = blockIdx.x * 256 + lid;
    const int b = idx >> 9, j = idx & 511;
    Za[(long)b * 262144 + j] = st0[idx];
    return;
  }
  if (op == 8) {            // K21uH[n][k] = Kr[512+n][k] (f16, unscaled)
    if (blockIdx.x >= 256) return;
    const int base = (blockIdx.x * 256 + lid) * 4;
    #pragma unroll
    for (int q = 0; q < 4; ++q) {
      const int e = base + q;
      const int n = e >> 9, k = e & 511;
      K21uH[e] = (_Float16)Kr[(long)(512 + n) * 1024 + k];
    }
    return;
  }
  if (op == 9) {            // zerosH = 0 (32768 f16)
    if (blockIdx.x >= 32) return;
    const int base = (blockIdx.x * 256 + lid);
    *(f16x4*)&zerosH[base * 4] = f16x4{0, 0, 0, 0};
    return;
  }
  __shared__ float t[32][33];
  if (op <= 1) {            // 1024x1024 transposes of Kr
    if (blockIdx.x >= 1024) return;
    const int bx = blockIdx.x & 31, by = blockIdx.x >> 5;
    const long I0 = (long)bx * 32, J0 = (long)by * 32;
    #pragma unroll
    for (int k = 0; k < 4; ++k)
      t[ty * 4 + k][tx] = Kr[(J0 + ty * 4 + k) * 1024 + I0 + tx];
    __syncthreads();
    #pragma unroll
    for (int k = 0; k < 4; ++k) {
      const long i = I0 + ty * 4 + k, j = J0 + tx;
      if (op == 0) Krt[i * 1024 + j] = t[tx][ty * 4 + k];
      else         KrH[i * 1024 + j] = (_Float16)t[tx][ty * 4 + k];
    }
  } else {                  // 512x512 transposes: op2 St, op3 X0, op6 K11u, op7 K12u
    if (blockIdx.x >= 256) return;
    const int bx = blockIdx.x & 15, by = blockIdx.x >> 4;
    const long I0 = (long)bx * 32, J0 = (long)by * 32;
    const float* src;
    long ld, coff;
    if (op == 6) { src = Kr; ld = 1024; coff = 0; }
    else if (op == 7) { src = Kr; ld = 1024; coff = 512; }
    else { src = S; ld = 512; coff = 0; }
    #pragma unroll
    for (int k = 0; k < 4; ++k)
      t[ty * 4 + k][tx] = src[(J0 + ty * 4 + k) * ld + coff + I0 + tx];
    __syncthreads();
    #pragma unroll
    for (int k = 0; k < 4; ++k) {
      const long i = I0 + ty * 4 + k, j = J0 + tx;
      if (op == 2) St[i * 512 + j] = t[tx][ty * 4 + k];
      else if (op == 3) Xa[i * 512 + j] = ((i == j) ? 2.0f : 0.0f) - t[tx][ty * 4 + k];
      else if (op == 6) K11u[i * 512 + j] = t[tx][ty * 4 + k];
      else K12u[i * 512 + j] = t[tx][ty * 4 + k];
    }
  }
}

// Post-scalar rescale: fold invk/gamma into the unscaled f16/f32 operands.
__global__ void prep2_k(const float* Kr, const float* sc, _Float16* ABstH,
                        _Float16* StackH, const _Float16* BtuH,
                        _Float16* CtDtH, float* APf2) {
  const int op = blockIdx.y;
  const int lid = threadIdx.y * 32 + threadIdx.x;
  const float invk = sc[0], gik = sc[2];
  const float ik2 = invk * invk, ik2g = ik2 * sc[1];
  if (op == 0) {            // ABstH [512][1024]: AtH*=invk ; BtH = gik*BtuH
    if (blockIdx.x >= 512) return;
    const int base = (blockIdx.x * 256 + lid) * 4;
    #pragma unroll
    for (int q = 0; q < 4; ++q) {
      const int e = base + q;
      const int n = e >> 10, c = e & 1023;
      if (c < 512) ABstH[e] = (_Float16)((float)ABstH[e] * invk);
      else ABstH[e] = (_Float16)(gik * (float)BtuH[(long)n * 512 + (c - 512)]);
    }
  } else if (op == 1) {     // StackH [512][1536]: At2*=ik2 ; BtAt*=ik2g ; Bt=gik*BtuH
    if (blockIdx.x >= 768) return;
    const int base = (blockIdx.x * 256 + lid) * 4;
    #pragma unroll
    for (int q = 0; q < 4; ++q) {
      const int e = base + q;
      const int n = e / 1536, c = e - n * 1536;
      float v;
      if (c < 512) v = (float)StackH[e] * ik2;
      else if (c < 1024) v = (float)StackH[e] * ik2g;
      else v = gik * (float)BtuH[(long)n * 512 + (c - 1024)];
      StackH[e] = (_Float16)v;
    }
  } else if (op == 2) {     // CtDtH [512][1024]: Ct*=invk ; Dt = gik*K22
    if (blockIdx.x >= 512) return;
    const int base = (blockIdx.x * 256 + lid) * 4;
    #pragma unroll
    for (int q = 0; q < 4; ++q) {
      const int e = base + q;
      const int n = e >> 10, c = e & 1023;
      if (c < 512) CtDtH[e] = (_Float16)((float)CtDtH[e] * invk);
      else CtDtH[e] = (_Float16)(gik * Kr[(long)(512 + n) * 1024 + 512 + (c - 512)]);
    }
  } else {                  // APf2 f32 *= ik2
    if (blockIdx.x >= 256) return;
    const int base = (blockIdx.x * 256 + lid) * 4;
    #pragma unroll
    for (int q = 0; q < 4; ++q) APf2[base + q] *= ik2;
  }
}

// sigma from scale chain: ln l1(M0) = sum_{k<nsq} 2^-k ln s_k + 2^-nsq ln s_nsq
__global__ void scalar_k(const float* P, int nsq, const float* lg, float* sc) {
  __shared__ float red[256];
  __shared__ float sv[16];
  const int tid = threadIdx.x;
  for (int k = 0; k <= nsq; ++k) {
    red[tid] = P[k * 256 + tid];
    __syncthreads();
    for (int st = 128; st > 0; st >>= 1) {
      if (tid < st) red[tid] += red[tid + st];
      __syncthreads();
    }
    if (tid == 0) sv[k] = red[0];
    __syncthreads();
  }
  if (tid != 0) return;
  double lnl = 0.0, wgt = 1.0;
  for (int k = 0; k <= nsq; ++k) {
    double sk = sqrt((double)sv[k]);
    lnl += wgt * log(sk);
    if (k < nsq) wgt *= 0.5;
  }
  double sigma = exp(0.5 * lnl);
  if (sigma < 1e-5) sigma = 1e-5;
  const double invk = 1.0 / (sigma + 0.002);
  const double g = exp((double)lg[0]);
  sc[0] = (float)invk;        // invk
  sc[1] = (float)g;           // gamma
  sc[2] = (float)(g * invk);  // gamma*invk
}

static inline Addr lin(long stride) {
  Addr a; a.hi = 0; a.lo = stride; a.sh = 20; a.msk = 0xFFFFF; return a;
}
static inline Addr two(int sh, long hi, int msk, long lo) {
  Addr a; a.hi = hi; a.lo = lo; a.sh = sh; a.msk = msk; return a;
}
static inline GP gp0() {
  GP p; memset(&p, 0, sizeof(p)); p.alpha = 1.0f; p.beta = 1.0f; return p;
}

extern "C" void kernel_launch(void* const* d_in, const int* in_sizes, int n_in,
                              void* d_out, int out_size, void* d_ws, size_t ws_size,
                              hipStream_t stream) {
  (void)in_sizes; (void)n_in; (void)out_size; (void)ws_size;
  const float* u    = (const float*)d_in[0];  // [16][2048][512]
  const float* st0  = (const float*)d_in[1];  // [16][512]
  const float* S    = (const float*)d_in[2];  // [512][512]
  const float* Kr   = (const float*)d_in[3];  // [1024][1024]
  const float* lgam = (const float*)d_in[4];  // [1]

  float* outp   = (float*)d_out;                       // [16][2048][512]
  float* states = outp + (long)16 * 2048 * 512;        // [16][2049][512]
  float* ws = (float*)d_ws;

  const int NSQ = 8;
  float* sc = ws;                 // 3 scalars
  float* P  = ws + 64;            // (NSQ+1)*256 frobenius partials
  float* base = ws + 3456;

  // ws layout (float offsets from ws):
  float* Krt = base;                  // 1024^2 f32 (dead after d1); MbH overlays
  _Float16* MbH = (_Float16*)base;
  float* Ma  = base + 1048576;
  float* Mb  = base + 2097152;        // ends ws+3149184
  _Float16* CtDtH  = (_Float16*)(ws + 3149248);   // [512][1024] (ends 3411392)
  _Float16* MaH    = (_Float16*)(ws + 3419584);   // [1024][1024] (ends 3943872)
  _Float16* StackH = (_Float16*)(ws + 3943872);   // [512][1536] (ends 4337088)
  _Float16* zerosH = (_Float16*)(ws + 4337088);   // [512][64] zeros (64 KiB)

  // outp region (dead before final GEMM writes)
  float* Za  = outp;                  // [16][512][512] KS ping
  float* Zb  = outp + 4194304;        // [16][512][512] KS pong
  float* APb = outp + 8388608;        // At^j f32, j=2..8
  float* Tb  = outp + 10223616;       // T(k) f32, k=1..2 (+ temp slots)
  // T slots double as unscaled temporaries (dead before each T write):
  float* K11u = Tb;                   // dead after squaring k=6; T1 @ pass1 j=6
  float* K12u = Tb + 262144;          // dead after k=7; T2 @ pass1 j=8
  float* AtU  = Tb + 524288;          // dead after k=8 (slot never reused)
  float* BtU  = Tb + 786432;          // dead after k=8 (slot never reused)
  _Float16* h16   = (_Float16*)(outp + 12320768);
  _Float16* ABstH = h16;                       // [512][1024]: AtH | BtH
  _Float16* APH_  = h16 + 524288;              // At^j shadows j=3..8 (6 slots)
  _Float16* TmH_  = h16 + 2097152;             // T(k) shadows k=1..2
  _Float16* XaH   = h16 + 4194304;
  _Float16* XbH   = XaH + 262144;
  _Float16* YnH   = XbH + 262144;
  _Float16* WH    = YnH + 262144;
  _Float16* K21uH = WH + 262144;
  _Float16* KrH   = K21uH + 262144;            // [1024][1024] (ends h16+6553600)
  _Float16* BtuH  = h16 + 6553600;             // [512][512] (ends h16+6815744)
  float* St = outp + 15728640;                 // f32 Newton buffers
  float* Xa = outp + 15990784;
  float* Xb = outp + 16252928;
  float* Yn = outp + 16515072;

  auto APf = [&](int j) -> float* {
    return APb + (long)(j - 2) * 262144;       // j=2..8
  };
  // f16 shadow of At^j: j=1 in ABstH, j=2 in StackH, j>=3 in APH_
  auto APHp = [&](int j) -> const _Float16* {
    if (j == 1) return ABstH;
    if (j == 2) return StackH;
    return APH_ + (long)(j - 3) * 262144;
  };
  auto APHl = [&](int j) { return (j == 1) ? 1024 : ((j == 2) ? 1536 : 512); };
  auto Tmf = [&](int k) -> float* { return (k == 0) ? APf(8) : Tb + (long)(k - 1) * 262144; };
  auto TmH = [&](int k) -> _Float16* {
    return (k == 0) ? (_Float16*)APHp(8) : TmH_ + (long)(k - 1) * 262144;
  };

  auto launch64 = [&](const GP* gs, int nb) {
    GPB pb; memset(&pb, 0, sizeof(pb));
    int mx = 0;
    for (int i = 0; i < nb; ++i) {
      pb.g[i] = gs[i];
      int b = ((gs[i].M + 63) / 64) * ((gs[i].N + 63) / 64);
      if (b > mx) mx = b;
    }
    gemm_u64<<<dim3(mx, nb), dim3(256), 0, stream>>>(pb);
  };
  auto launch128 = [&](const GP* gs, int nb) {
    GPB pb; memset(&pb, 0, sizeof(pb));
    int mx = 0;
    for (int i = 0; i < nb; ++i) {
      pb.g[i] = gs[i];
      int b = ((gs[i].M + 127) / 128) * ((gs[i].N + 127) / 128);
      if (b > mx) mx = b;
    }
    gemm_u128<<<dim3(mx, nb), dim3(256), 0, stream>>>(pb);
  };

  // 512^3 helper: C f32 (optional) + f16 transposed shadow (optional)
  auto mmh = [&](const float* A, const _Float16* Bh, int ldbh,
                 float* C, _Float16* Ch, int ldh) {
    GP g = gp0(); g.M = 512; g.N = 512; g.K1 = 512;
    g.A1 = A; g.a1 = lin(512);
    g.Bh = Bh; g.ldbh = ldbh;
    g.C1 = C; g.c1 = lin(512);
    g.C1h = Ch; g.ldh = ldh;
    return g;
  };
  auto cpGP = [&](const float* src, Addr sa, float* dst, Addr da, int M) {
    GP g = gp0(); g.M = M; g.N = 512; g.K1 = 64;
    g.A1 = src; g.a1 = sa;
    g.Bh = zerosH; g.ldbh = 64;
    g.E1 = src; g.e1 = sa; g.beta = 1.0f;
    g.C1 = dst; g.c1 = da;
    return g;
  };

  prep1_k<<<dim3(1024, 10), dim3(32, 8), 0, stream>>>(S, Kr, st0, Krt, KrH,
                                                      St, Xa, XaH, Za,
                                                      K11u, K12u, K21uH, zerosH);

  // ---- phase A: squaring chain; Newton rides k=1..5; unscaled ABCD rides
  //      k=6 (W~, Ct~), k=7 (At~, Bt~), k=8 (At~^2, Bt~At~) ----
  {
    GP gs[2];
    gs[0] = gp0();
    gs[0].M = 1024; gs[0].N = 1024; gs[0].K1 = 1024;
    gs[0].A1 = Krt; gs[0].a1 = lin(1024);
    gs[0].Bh = KrH; gs[0].ldbh = 1024;
    gs[0].C1 = Ma; gs[0].c1 = lin(1024);
    gs[0].C1h = MaH; gs[0].ldh = 1024;     // M0 symmetric -> shadow == M0
    gs[0].fout = P;
    gs[1] = mmh(St, XaH, 512, Yn, YnH, 512);   // Newton 1a
    launch64(gs, 2);
  }
  for (int k = 1; k <= NSQ; ++k) {
    const bool odd = (k % 2 == 1);
    float* cur = odd ? Ma : Mb;
    float* nxt = odd ? Mb : Ma;
    _Float16* curH = odd ? MaH : MbH;
    _Float16* nxtH = odd ? MbH : MaH;
    GP gs[3];
    gs[0] = gp0();
    gs[0].M = 1024; gs[0].N = 1024; gs[0].K1 = 1024;
    gs[0].A1 = cur; gs[0].a1 = lin(1024);
    gs[0].Bh = curH; gs[0].ldbh = 1024;    // symmetric f16 shadow as B
    gs[0].C1 = nxt; gs[0].c1 = lin(1024);
    gs[0].C1h = nxtH; gs[0].ldh = 1024;
    gs[0].fin = P + (long)(k - 1) * 256;   // A *= sscale, alpha *= sscale
    gs[0].fout = P + (long)k * 256;
    int nb = 1;
    if (k <= 5) {
      if (odd) {           // Newton b-step: X' = 2X - X@Yn
        float* cx = (k == 1 || k == 5) ? Xa : Xb;
        float* nx = (k == 1 || k == 5) ? Xb : Xa;
        _Float16* nxH = (k == 1 || k == 5) ? XbH : XaH;
        GP h = mmh(cx, YnH, 512, nx, nxH, 512);
        h.alpha = -1.0f; h.E1 = cx; h.e1 = lin(512); h.beta = 2.0f;
        gs[nb++] = h;
      } else {             // Newton a-step: Yn = St @ X
        _Float16* cxH = (k == 2) ? XbH : XaH;
        gs[nb++] = mmh(St, cxH, 512, Yn, YnH, 512);
      }
    } else if (k == 6) {
      gs[nb++] = mmh(K11u, XbH, 512, nullptr, WH, 512);      // W~ = K11^T@SinvT
      gs[nb++] = mmh(St, K21uH, 512, nullptr, CtDtH, 1024);  // Ct~ (unscaled)
    } else if (k == 7) {
      gs[nb++] = mmh(St, WH, 512, AtU, ABstH, 1024);         // At~ + At~H
      gs[nb++] = mmh(K12u, XbH, 512, BtU, BtuH, 512);        // Bt~ + Bt~H
    } else {
      gs[nb++] = mmh(AtU, ABstH, 1024, APf(2), StackH, 1536);     // At~^2
      gs[nb++] = mmh(BtU, ABstH, 1024, nullptr, StackH + 512, 1536); // Bt~At~
    }
    launch64(gs, nb);
  }
  scalar_k<<<1, 256, 0, stream>>>(P, NSQ, lgam, sc);
  prep2_k<<<dim3(768, 4), dim3(32, 8), 0, stream>>>(Kr, sc, ABstH, StackH,
                                                    BtuH, CtDtH, APf(2));

  // Addressing constants (L=8, 256 chunks/batch)
  const Addr A_u8   = two(8, 1048576, 255, 4096);
  const Addr A_s8   = two(8, 1049088, 255, 4096);
  const Addr A_z    = two(8, 262144, 255, 512);
  const Addr A_srow = two(11, 1049088, 2047, 512);

  // ---- pass1 radix-2: 4 serial steps j=2,4,6,8 (contiguous u-pair)
  //   l_j = l_{j-2}@At^2 + u_{j-2}@BtAt + u_{j-1}@Bt ; B = [At2|BtAt|Bt] stack
  //   riders: s1: At^3,At^4 | s2: At^5..8 | s3: T1=Q^2 | s4: T2=Q^4
  for (int j = 2; j <= 8; j += 2) {
    GP gs[5];
    int nb = 0;
    GP m = gp0();
    m.M = 4096; m.N = 512;
    if (j == 2) {
      m.K1 = 1024; m.A1 = u; m.a1 = A_u8;        // u rows 8c+0,8c+1 contiguous
      m.Bh = StackH + 512; m.ldbh = 1536;        // rows [BtAt; Bt]
    } else {
      m.K1 = 512; m.A1 = states + (long)(j - 2) * 512; m.a1 = A_s8;
      m.K2 = 1024; m.A2 = u + (long)(j - 2) * 512; m.a2 = A_u8;
      m.Bh = StackH; m.ldbh = 1536;              // rows [At2; BtAt; Bt]
    }
    if (j == 8) { m.C1 = Za + 512; m.c1 = A_z; }
    else { m.C1 = states + (long)j * 512; m.c1 = A_s8; }
    gs[nb++] = m;
    if (j == 2) {
      gs[nb++] = mmh(APf(2), ABstH, 1024, APf(3), APH_ + 0, 512);       // At^3
      gs[nb++] = mmh(APf(2), StackH, 1536, APf(4), APH_ + 262144, 512); // At^4
    } else if (j == 4) {
      for (int i = 1; i <= 4; ++i)
        gs[nb++] = mmh(APf(4), APHp(i), APHl(i), APf(4 + i),
                       APH_ + (long)(i + 1) * 262144, 512);             // At^5..8
    } else if (j == 6) {
      gs[nb++] = mmh(Tmf(0), TmH(0), 512, Tmf(1), TmH(1), 512);        // T1
    } else {
      gs[nb++] = mmh(Tmf(1), TmH(1), 512, Tmf(2), TmH(2), 512);        // T2
    }
    launch64(gs, nb);
  }

  // ---- Truncated Kogge-Stone (3 rounds, window 8): ||Q||<=0.2 =>
  //      truncation error <= ||Q^8||*||Y|| ~ 1e-5, far below threshold.
  //      odd-fill rides round 0; carry-copy folded in ----
  for (int k = 0; k <= 2; ++k) {
    const int s = 1 << k;
    float* Zs = (k % 2 == 0) ? Za : Zb;
    float* Zd = (k % 2 == 0) ? Zb : Za;
    GP gs[7];
    int nb = 0;
    GP m = gp0();
    m.M = 4096; m.N = 512; m.K1 = 512;
    m.A1 = Zs; m.a1 = A_z;
    m.Bh = TmH(k); m.ldbh = 512;
    m.E1 = Zs + (long)s * 512; m.e1 = A_z; m.beta = 1.0f;
    m.C1 = Zd + (long)s * 512; m.c1 = A_z;
    gs[nb++] = m;
    const Addr lowA = two(k, 262144, s - 1, 512);
    gs[nb++] = cpGP(Zs, lowA, Zd, lowA, 16 * s);
    if (k == 0) {
      // odd locals: l_1 = u_0@Bt; l_j = l_{j-1}@At + u_{j-1}@Bt (j=3,5,7)
      for (int j = 1; j <= 7; j += 2) {
        GP g = gp0();
        g.M = 4096; g.N = 512;
        if (j == 1) {
          g.K1 = 512; g.A1 = u; g.a1 = A_u8;
          g.Bh = ABstH + 512; g.ldbh = 1024;     // Bt only
        } else {
          g.K1 = 512; g.A1 = states + (long)(j - 1) * 512; g.a1 = A_s8;
          g.K2 = 512; g.A2 = u + (long)(j - 1) * 512; g.a2 = A_u8;
          g.Bh = ABstH; g.ldbh = 1024;           // [At; Bt]
        }
        g.C1 = states + (long)j * 512; g.c1 = A_s8;
        gs[nb++] = g;
      }
    }
    launch64(gs, nb);
  }
  float* Zf = Zb;   // rounds 0,1,2 end in Zb

  // ---- corrections + states-extreme copies (one dispatch) ----
  {
    GP gs[9];
    for (int j = 1; j <= 7; ++j) {
      GP g = gp0();
      g.M = 4096; g.N = 512; g.K1 = 512;
      g.A1 = Zf; g.a1 = A_z;
      g.Bh = APHp(j); g.ldbh = APHl(j);
      g.C2 = states + (long)j * 512; g.c2 = A_s8;
      g.E2 = states + (long)j * 512; g.e2 = A_s8;
      gs[j - 1] = g;
    }
    gs[7] = cpGP(Zf, A_z, states, A_s8, 4096);
    gs[8] = cpGP(Zf + (long)256 * 512, lin(262144),
                 states + (long)2048 * 512, lin(1049088), 16);
    launch128(gs, 9);
  }

  // ---- output = states[:, :T] @ Ct + u @ Dt ----
  {
    GP g = gp0();
    g.M = 32768; g.N = 512;
    g.K1 = 512; g.A1 = states; g.a1 = A_srow;
    g.K2 = 512; g.A2 = u; g.a2 = lin(512);
    g.Bh = CtDtH; g.ldbh = 1024;
    g.C1 = outp; g.c1 = lin(512);
    launch128(&g, 1);
  }
}

// Round 19
// 577.301 us; speedup vs baseline: 1.0978x; 1.0350x over previous
//
#include <hip/hip_runtime.h>
#include <string.h>

typedef _Float16 f16x8 __attribute__((ext_vector_type(8)));
typedef _Float16 f16x4 __attribute__((ext_vector_type(4)));
typedef __fp16   hf2   __attribute__((ext_vector_type(2)));
typedef float    f32x4 __attribute__((ext_vector_type(4)));

// Generic 2-level row addressing: addr(r) = (r>>sh)*hi + (r&msk)*lo   (in elements)
struct Addr { long hi; long lo; int sh; int msk; };

__device__ __forceinline__ long raddr(const Addr a, int r) {
  return ((long)(r >> a.sh)) * a.hi + ((long)(r & a.msk)) * a.lo;
}

struct GP {
  int M, N, K1, K2;
  const float* A1; Addr a1;    // K-segment 1 rows (f32)
  const float* A2; Addr a2;    // K-segment 2 rows (optional, K2>0)
  const _Float16* Bh; int ldbh;// f16 [n][k] pre-transposed B operand
  const float* scale;          // optional: alpha *= *scale
  float alpha;
  const float* E1; Addr e1; float beta;   // C1 = alpha*acc + beta*E1
  float* C1; Addr c1;
  _Float16* C1h; int ldh;      // optional f16 transposed shadow of C1 value
  float* C2; Addr c2;          // C2 = alpha*acc + E2
  const float* E2; Addr e2;
  const float* fin;            // 256 partials: sscale=1/sqrt(sum); A*=sscale, alpha*=sscale
  float* fout;                 // per-block sum of squares of written values
};

struct GPB { GP g[10]; };

__device__ __forceinline__ f16x4 pk4s(f32x4 v, float ss) {
  hf2 lo = __builtin_amdgcn_cvt_pkrtz(v[0] * ss, v[1] * ss);
  hf2 hi = __builtin_amdgcn_cvt_pkrtz(v[2] * ss, v[3] * ss);
  f16x4 h;
  h[0] = (_Float16)lo[0]; h[1] = (_Float16)lo[1];
  h[2] = (_Float16)hi[0]; h[3] = (_Float16)hi[1];
  return h;
}

// Tiled GEMM, f32 A / f16 B -> f16 LDS -> f32 accum. 4 waves (2x2), single
// LDS buffer. DEEP=true (BM=64, serial latency-bound dispatches): 3 register
// sets, loads issue 2 tiles (~1400cy) ahead of consumption. DEEP=false
// (BM=128, parallel dispatches): 2-set pipeline — TLP covers latency there;
// DEEP at BM=128 measured -16% (round 18: extra barriers + rotate VALU).
// fin: A staged *sscale and alpha *= sscale (squaring-chain normalization).
// Requires (K1+K2) % 64 == 0, N % BN == 0.
template<int BM, bool DEEP>
__device__ __forceinline__ void gemm_body(const GP& p) {
  constexpr int BN = BM;
  constexpr int WT = BM / 2;
  constexpr int FM = WT / 16;
  constexpr int NAQ = BM / 32;                   // A f32x4 loads per thread
  constexpr int NBH = BN / 64;                   // B f16x8 loads per thread
  __shared__ _Float16 As[BM * 40];
  __shared__ _Float16 Bs[BN * 40];
  __shared__ float red[256];
  const int tid = threadIdx.x;
  const int nbn = (p.N + BN - 1) / BN;
  const int nbm = (p.M + BM - 1) / BM;
  if ((int)blockIdx.x >= nbm * nbn) return;
  int bm, bn;
  {
    const int bid = blockIdx.x;
    if ((nbm & 7) == 0) {   // stripe-XCD swizzle
      bm = (bid & 7) + ((bid >> 3) / nbn) * 8;
      bn = (bid >> 3) % nbn;
    } else {
      bm = bid / nbn; bn = bid - bm * nbn;
    }
  }
  const int m0 = bm * BM, n0 = bn * BN;

  float sscale = 1.0f;
  if (p.fin) {
    red[tid] = p.fin[tid];
    __syncthreads();
    for (int st = 128; st > 0; st >>= 1) {
      if (tid < st) red[tid] += red[tid + st];
      __syncthreads();
    }
    sscale = 1.0f / sqrtf(red[0]);
    __syncthreads();
  }
  float alpha = p.alpha;
  if (p.scale) alpha *= p.scale[0];
  if (p.fin) alpha *= sscale;

  const int w = tid >> 6, l = tid & 63;
  const int wm = w >> 1, wn = w & 1;
  const int lr = l & 15, lg = l >> 4;

  f32x4 acc[FM][FM];
  #pragma unroll
  for (int m = 0; m < FM; ++m)
    #pragma unroll
    for (int n = 0; n < FM; ++n) acc[m][n] = {0.f, 0.f, 0.f, 0.f};

  const int Kt = p.K1 + p.K2;

  f32x4 aR0[NAQ], aR1[NAQ];
  f16x8 b2R0[NBH], b2R1[NBH];

  auto loadT = [&](int k0, f32x4* aR, f16x8* b2R) {
    const float* Ab; Addr aa; long kl;
    if (k0 < p.K1) { Ab = p.A1; aa = p.a1; kl = k0; }
    else           { Ab = p.A2; aa = p.a2; kl = (long)k0 - p.K1; }
    #pragma unroll
    for (int i = 0; i < NAQ; ++i) {
      const int gq = tid + (i << 8);
      const int ar_ = gq >> 3, kq = gq & 7;
      f32x4 v = {0.f, 0.f, 0.f, 0.f};
      if (m0 + ar_ < p.M) v = *(const f32x4*)(Ab + raddr(aa, m0 + ar_) + kl + kq * 4);
      aR[i] = v;
    }
    #pragma unroll
    for (int i = 0; i < NBH; ++i) {
      const int row = (tid >> 2) + i * 64;
      b2R[i] = *(const f16x8*)(p.Bh + (long)(n0 + row) * p.ldbh + k0 + (tid & 3) * 8);
    }
  };
  auto storeLDS = [&](const f32x4* aR, const f16x8* b2R) {
    #pragma unroll
    for (int i = 0; i < NAQ; ++i) {
      const int gq = tid + (i << 8);
      const int ar_ = gq >> 3, kq = gq & 7;
      *(f16x4*)&As[ar_ * 40 + kq * 4] = pk4s(aR[i], sscale);
    }
    #pragma unroll
    for (int i = 0; i < NBH; ++i) {
      const int row = (tid >> 2) + i * 64;
      *(f16x8*)&Bs[row * 40 + (tid & 3) * 8] = b2R[i];
    }
  };
  auto compute = [&]() {
    f16x8 a[FM], b[FM];
    #pragma unroll
    for (int m = 0; m < FM; ++m)
      a[m] = *(const f16x8*)&As[(wm * WT + m * 16 + lr) * 40 + lg * 8];
    #pragma unroll
    for (int n = 0; n < FM; ++n)
      b[n] = *(const f16x8*)&Bs[(wn * WT + n * 16 + lr) * 40 + lg * 8];
    #pragma unroll
    for (int m = 0; m < FM; ++m)
      #pragma unroll
      for (int n = 0; n < FM; ++n)
        acc[m][n] = __builtin_amdgcn_mfma_f32_16x16x32_f16(a[m], b[n], acc[m][n], 0, 0, 0);
  };

  if constexpr (DEEP) {
    f32x4 aRC[NAQ];
    f16x8 bRC[NBH];
    loadT(0, aR0, b2R0);
    if (Kt > 32) loadT(32, aR1, b2R1);
    for (int k0 = 0; k0 < Kt; k0 += 32) {
      if (k0 + 64 < Kt) loadT(k0 + 64, aRC, bRC);   // 2 tiles ahead
      storeLDS(aR0, b2R0);
      __syncthreads();
      compute();
      __syncthreads();
      #pragma unroll
      for (int i = 0; i < NAQ; ++i) aR0[i] = aR1[i];
      #pragma unroll
      for (int i = 0; i < NBH; ++i) b2R0[i] = b2R1[i];
      #pragma unroll
      for (int i = 0; i < NAQ; ++i) aR1[i] = aRC[i];
      #pragma unroll
      for (int i = 0; i < NBH; ++i) b2R1[i] = bRC[i];
    }
  } else {
    loadT(0, aR0, b2R0);
    for (int k0 = 0; k0 < Kt; k0 += 64) {
      storeLDS(aR0, b2R0);
      __syncthreads();
      loadT(k0 + 32, aR1, b2R1);   // prefetch overlaps compute
      compute();
      __syncthreads();
      storeLDS(aR1, b2R1);
      __syncthreads();
      if (k0 + 64 < Kt) loadT(k0 + 64, aR0, b2R0);
      compute();
      __syncthreads();
    }
  }

  float ssq = 0.0f;
  #pragma unroll
  for (int m = 0; m < FM; ++m) {
    #pragma unroll
    for (int n = 0; n < FM; ++n) {
      #pragma unroll
      for (int rr = 0; rr < 4; ++rr) {
        const int ro = m0 + wm * WT + m * 16 + lg * 4 + rr;
        const int no = n0 + wn * WT + n * 16 + lr;
        if (ro < p.M) {
          float val = alpha * acc[m][n][rr];
          float o1 = val;
          if (p.E1) o1 += p.beta * p.E1[raddr(p.e1, ro) + no];
          if (p.C1) p.C1[raddr(p.c1, ro) + no] = o1;
          if (p.C1h) p.C1h[(long)no * p.ldh + ro] = (_Float16)o1;
          if (p.C2) p.C2[raddr(p.c2, ro) + no] = val + p.E2[raddr(p.e2, ro) + no];
          ssq += val * val;
        }
      }
    }
  }
  if (p.fout) {
    __syncthreads();
    red[tid] = ssq;
    __syncthreads();
    for (int st = 128; st > 0; st >>= 1) {
      if (tid < st) red[tid] += red[tid + st];
      __syncthreads();
    }
    if (tid == 0) p.fout[blockIdx.x] = red[0];
  }
}

__global__ __launch_bounds__(256) void gemm_u64(GPB pb)  { gemm_body<64, true>(pb.g[blockIdx.y]); }
__global__ __launch_bounds__(256) void gemm_u128(GPB pb) { gemm_body<128, false>(pb.g[blockIdx.y]); }

// Fused prep before squaring chain: Krt, KrH, St, X0, X0H, Za-init,
// K11u/K12u (unscaled f32 transposes), K21uH (unscaled f16), zerosH
__global__ void prep1_k(const float* S, const float* Kr, const float* st0,
                        float* Krt, _Float16* KrH, float* St, float* Xa,
                        _Float16* XaH, float* Za,
                        float* K11u, float* K12u, _Float16* K21uH,
                        _Float16* zerosH) {
  const int op = blockIdx.y;
  const int tx = threadIdx.x, ty = threadIdx.y;
  const int lid = ty * 32 + tx;
  if (op == 4) {            // XaH = 2I - S (direct f16)
    if (blockIdx.x >= 256) return;
    const int base = (blockIdx.x * 256 + lid) * 4;
    #pragma unroll
    for (int q = 0; q < 4; ++q) {
      const int e = base + q;
      const int i = e >> 9, j = e & 511;
      XaH[e] = (_Float16)(((i == j) ? 2.0f : 0.0f) - S[(long)i * 512 + j]);
    }
    return;
  }
  if (op == 5) {            // Za[b][0] = st0[b]
    if (blockIdx.x >= 32) return;
    const int idx = blockIdx.x * 256 + lid;
    const int b = idx >> 9, j = idx & 511;
    Za[(long)b * 262144 + j] = st0[idx];
    return;
  }
  if (op == 8) {            // K21uH[n][k] = Kr[512+n][k] (f16, unscaled)
    if (blockIdx.x >= 256) return;
    const int base = (blockIdx.x * 256 + lid) * 4;
    #pragma unroll
    for (int q = 0; q < 4; ++q) {
      const int e = base + q;
      const int n = e >> 9, k = e & 511;
      K21uH[e] = (_Float16)Kr[(long)(512 + n) * 1024 + k];
    }
    return;
  }
  if (op == 9) {            // zerosH = 0 (32768 f16)
    if (blockIdx.x >= 32) return;
    const int base = (blockIdx.x * 256 + lid);
    *(f16x4*)&zerosH[base * 4] = f16x4{0, 0, 0, 0};
    return;
  }
  __shared__ float t[32][33];
  if (op <= 1) {            // 1024x1024 transposes of Kr
    if (blockIdx.x >= 1024) return;
    const int bx = blockIdx.x & 31, by = blockIdx.x >> 5;
    const long I0 = (long)bx * 32, J0 = (long)by * 32;
    #pragma unroll
    for (int k = 0; k < 4; ++k)
      t[ty * 4 + k][tx] = Kr[(J0 + ty * 4 + k) * 1024 + I0 + tx];
    __syncthreads();
    #pragma unroll
    for (int k = 0; k < 4; ++k) {
      const long i = I0 + ty * 4 + k, j = J0 + tx;
      if (op == 0) Krt[i * 1024 + j] = t[tx][ty * 4 + k];
      else         KrH[i * 1024 + j] = (_Float16)t[tx][ty * 4 + k];
    }
  } else {                  // 512x512 transposes: op2 St, op3 X0, op6 K11u, op7 K12u
    if (blockIdx.x >= 256) return;
    const int bx = blockIdx.x & 15, by = blockIdx.x >> 4;
    const long I0 = (long)bx * 32, J0 = (long)by * 32;
    const float* src;
    long ld, coff;
    if (op == 6) { src = Kr; ld = 1024; coff = 0; }
    else if (op == 7) { src = Kr; ld = 1024; coff = 512; }
    else { src = S; ld = 512; coff = 0; }
    #pragma unroll
    for (int k = 0; k < 4; ++k)
      t[ty * 4 + k][tx] = src[(J0 + ty * 4 + k) * ld + coff + I0 + tx];
    __syncthreads();
    #pragma unroll
    for (int k = 0; k < 4; ++k) {
      const long i = I0 + ty * 4 + k, j = J0 + tx;
      if (op == 2) St[i * 512 + j] = t[tx][ty * 4 + k];
      else if (op == 3) Xa[i * 512 + j] = ((i == j) ? 2.0f : 0.0f) - t[tx][ty * 4 + k];
      else if (op == 6) K11u[i * 512 + j] = t[tx][ty * 4 + k];
      else K12u[i * 512 + j] = t[tx][ty * 4 + k];
    }
  }
}

// Post-scalar rescale: fold invk/gamma into the unscaled f16/f32 operands.
__global__ void prep2_k(const float* Kr, const float* sc, _Float16* ABstH,
                        _Float16* StackH, const _Float16* BtuH,
                        _Float16* CtDtH, float* APf2) {
  const int op = blockIdx.y;
  const int lid = threadIdx.y * 32 + threadIdx.x;
  const float invk = sc[0], gik = sc[2];
  const float ik2 = invk * invk, ik2g = ik2 * sc[1];
  if (op == 0) {            // ABstH [512][1024]: AtH*=invk ; BtH = gik*BtuH
    if (blockIdx.x >= 512) return;
    const int base = (blockIdx.x * 256 + lid) * 4;
    #pragma unroll
    for (int q = 0; q < 4; ++q) {
      const int e = base + q;
      const int n = e >> 10, c = e & 1023;
      if (c < 512) ABstH[e] = (_Float16)((float)ABstH[e] * invk);
      else ABstH[e] = (_Float16)(gik * (float)BtuH[(long)n * 512 + (c - 512)]);
    }
  } else if (op == 1) {     // StackH [512][1536]: At2*=ik2 ; BtAt*=ik2g ; Bt=gik*BtuH
    if (blockIdx.x >= 768) return;
    const int base = (blockIdx.x * 256 + lid) * 4;
    #pragma unroll
    for (int q = 0; q < 4; ++q) {
      const int e = base + q;
      const int n = e / 1536, c = e - n * 1536;
      float v;
      if (c < 512) v = (float)StackH[e] * ik2;
      else if (c < 1024) v = (float)StackH[e] * ik2g;
      else v = gik * (float)BtuH[(long)n * 512 + (c - 1024)];
      StackH[e] = (_Float16)v;
    }
  } else if (op == 2) {     // CtDtH [512][1024]: Ct*=invk ; Dt = gik*K22
    if (blockIdx.x >= 512) return;
    const int base = (blockIdx.x * 256 + lid) * 4;
    #pragma unroll
    for (int q = 0; q < 4; ++q) {
      const int e = base + q;
      const int n = e >> 10, c = e & 1023;
      if (c < 512) CtDtH[e] = (_Float16)((float)CtDtH[e] * invk);
      else CtDtH[e] = (_Float16)(gik * Kr[(long)(512 + n) * 1024 + 512 + (c - 512)]);
    }
  } else {                  // APf2 f32 *= ik2
    if (blockIdx.x >= 256) return;
    const int base = (blockIdx.x * 256 + lid) * 4;
    #pragma unroll
    for (int q = 0; q < 4; ++q) APf2[base + q] *= ik2;
  }
}

// sigma from scale chain: ln l1(M0) = sum_{k<nsq} 2^-k ln s_k + 2^-nsq ln s_nsq
__global__ void scalar_k(const float* P, int nsq, const float* lg, float* sc) {
  __shared__ float red[256];
  __shared__ float sv[16];
  const int tid = threadIdx.x;
  for (int k = 0; k <= nsq; ++k) {
    red[tid] = P[k * 256 + tid];
    __syncthreads();
    for (int st = 128; st > 0; st >>= 1) {
      if (tid < st) red[tid] += red[tid + st];
      __syncthreads();
    }
    if (tid == 0) sv[k] = red[0];
    __syncthreads();
  }
  if (tid != 0) return;
  double lnl = 0.0, wgt = 1.0;
  for (int k = 0; k <= nsq; ++k) {
    double sk = sqrt((double)sv[k]);
    lnl += wgt * log(sk);
    if (k < nsq) wgt *= 0.5;
  }
  double sigma = exp(0.5 * lnl);
  if (sigma < 1e-5) sigma = 1e-5;
  const double invk = 1.0 / (sigma + 0.002);
  const double g = exp((double)lg[0]);
  sc[0] = (float)invk;        // invk
  sc[1] = (float)g;           // gamma
  sc[2] = (float)(g * invk);  // gamma*invk
}

static inline Addr lin(long stride) {
  Addr a; a.hi = 0; a.lo = stride; a.sh = 20; a.msk = 0xFFFFF; return a;
}
static inline Addr two(int sh, long hi, int msk, long lo) {
  Addr a; a.hi = hi; a.lo = lo; a.sh = sh; a.msk = msk; return a;
}
static inline GP gp0() {
  GP p; memset(&p, 0, sizeof(p)); p.alpha = 1.0f; p.beta = 1.0f; return p;
}

extern "C" void kernel_launch(void* const* d_in, const int* in_sizes, int n_in,
                              void* d_out, int out_size, void* d_ws, size_t ws_size,
                              hipStream_t stream) {
  (void)in_sizes; (void)n_in; (void)out_size; (void)ws_size;
  const float* u    = (const float*)d_in[0];  // [16][2048][512]
  const float* st0  = (const float*)d_in[1];  // [16][512]
  const float* S    = (const float*)d_in[2];  // [512][512]
  const float* Kr   = (const float*)d_in[3];  // [1024][1024]
  const float* lgam = (const float*)d_in[4];  // [1]

  float* outp   = (float*)d_out;                       // [16][2048][512]
  float* states = outp + (long)16 * 2048 * 512;        // [16][2049][512]
  float* ws = (float*)d_ws;

  const int NSQ = 8;
  float* sc = ws;                 // 3 scalars
  float* P  = ws + 64;            // (NSQ+1)*256 frobenius partials
  float* base = ws + 3456;

  // ws layout (float offsets from ws):
  float* Krt = base;                  // 1024^2 f32 (dead after d1); MbH overlays
  _Float16* MbH = (_Float16*)base;
  float* Ma  = base + 1048576;
  float* Mb  = base + 2097152;        // ends ws+3149184
  _Float16* CtDtH  = (_Float16*)(ws + 3149248);   // [512][1024] (ends 3411392)
  _Float16* MaH    = (_Float16*)(ws + 3419584);   // [1024][1024] (ends 3943872)
  _Float16* StackH = (_Float16*)(ws + 3943872);   // [512][1536] (ends 4337088)
  _Float16* zerosH = (_Float16*)(ws + 4337088);   // [512][64] zeros (64 KiB)

  // outp region (dead before final GEMM writes)
  float* Za  = outp;                  // [16][512][512] KS ping
  float* Zb  = outp + 4194304;        // [16][512][512] KS pong
  float* APb = outp + 8388608;        // At^j f32, j=2..8
  float* Tb  = outp + 10223616;       // T(k) f32, k=1..2 (+ temp slots)
  // T slots double as unscaled temporaries (dead before each T write):
  float* K11u = Tb;                   // dead after squaring k=6; T1 @ pass1 j=6
  float* K12u = Tb + 262144;          // dead after k=7; T2 @ pass1 j=8
  float* AtU  = Tb + 524288;          // dead after k=8 (slot never reused)
  float* BtU  = Tb + 786432;          // dead after k=8 (slot never reused)
  _Float16* h16   = (_Float16*)(outp + 12320768);
  _Float16* ABstH = h16;                       // [512][1024]: AtH | BtH
  _Float16* APH_  = h16 + 524288;              // At^j shadows j=3..8 (6 slots)
  _Float16* TmH_  = h16 + 2097152;             // T(k) shadows k=1..2
  _Float16* XaH   = h16 + 4194304;
  _Float16* XbH   = XaH + 262144;
  _Float16* YnH   = XbH + 262144;
  _Float16* WH    = YnH + 262144;
  _Float16* K21uH = WH + 262144;
  _Float16* KrH   = K21uH + 262144;            // [1024][1024] (ends h16+6553600)
  _Float16* BtuH  = h16 + 6553600;             // [512][512] (ends h16+6815744)
  float* St = outp + 15728640;                 // f32 Newton buffers
  float* Xa = outp + 15990784;
  float* Xb = outp + 16252928;
  float* Yn = outp + 16515072;

  auto APf = [&](int j) -> float* {
    return APb + (long)(j - 2) * 262144;       // j=2..8
  };
  // f16 shadow of At^j: j=1 in ABstH, j=2 in StackH, j>=3 in APH_
  auto APHp = [&](int j) -> const _Float16* {
    if (j == 1) return ABstH;
    if (j == 2) return StackH;
    return APH_ + (long)(j - 3) * 262144;
  };
  auto APHl = [&](int j) { return (j == 1) ? 1024 : ((j == 2) ? 1536 : 512); };
  auto Tmf = [&](int k) -> float* { return (k == 0) ? APf(8) : Tb + (long)(k - 1) * 262144; };
  auto TmH = [&](int k) -> _Float16* {
    return (k == 0) ? (_Float16*)APHp(8) : TmH_ + (long)(k - 1) * 262144;
  };

  auto launch64 = [&](const GP* gs, int nb) {
    GPB pb; memset(&pb, 0, sizeof(pb));
    int mx = 0;
    for (int i = 0; i < nb; ++i) {
      pb.g[i] = gs[i];
      int b = ((gs[i].M + 63) / 64) * ((gs[i].N + 63) / 64);
      if (b > mx) mx = b;
    }
    gemm_u64<<<dim3(mx, nb), dim3(256), 0, stream>>>(pb);
  };
  auto launch128 = [&](const GP* gs, int nb) {
    GPB pb; memset(&pb, 0, sizeof(pb));
    int mx = 0;
    for (int i = 0; i < nb; ++i) {
      pb.g[i] = gs[i];
      int b = ((gs[i].M + 127) / 128) * ((gs[i].N + 127) / 128);
      if (b > mx) mx = b;
    }
    gemm_u128<<<dim3(mx, nb), dim3(256), 0, stream>>>(pb);
  };

  // 512^3 helper: C f32 (optional) + f16 transposed shadow (optional)
  auto mmh = [&](const float* A, const _Float16* Bh, int ldbh,
                 float* C, _Float16* Ch, int ldh) {
    GP g = gp0(); g.M = 512; g.N = 512; g.K1 = 512;
    g.A1 = A; g.a1 = lin(512);
    g.Bh = Bh; g.ldbh = ldbh;
    g.C1 = C; g.c1 = lin(512);
    g.C1h = Ch; g.ldh = ldh;
    return g;
  };
  auto cpGP = [&](const float* src, Addr sa, float* dst, Addr da, int M) {
    GP g = gp0(); g.M = M; g.N = 512; g.K1 = 64;
    g.A1 = src; g.a1 = sa;
    g.Bh = zerosH; g.ldbh = 64;
    g.E1 = src; g.e1 = sa; g.beta = 1.0f;
    g.C1 = dst; g.c1 = da;
    return g;
  };

  prep1_k<<<dim3(1024, 10), dim3(32, 8), 0, stream>>>(S, Kr, st0, Krt, KrH,
                                                      St, Xa, XaH, Za,
                                                      K11u, K12u, K21uH, zerosH);

  // ---- phase A: squaring chain; Newton rides k=1..5; unscaled ABCD rides
  //      k=6 (W~, Ct~), k=7 (At~, Bt~), k=8 (At~^2, Bt~At~) ----
  {
    GP gs[2];
    gs[0] = gp0();
    gs[0].M = 1024; gs[0].N = 1024; gs[0].K1 = 1024;
    gs[0].A1 = Krt; gs[0].a1 = lin(1024);
    gs[0].Bh = KrH; gs[0].ldbh = 1024;
    gs[0].C1 = Ma; gs[0].c1 = lin(1024);
    gs[0].C1h = MaH; gs[0].ldh = 1024;     // M0 symmetric -> shadow == M0
    gs[0].fout = P;
    gs[1] = mmh(St, XaH, 512, Yn, YnH, 512);   // Newton 1a
    launch64(gs, 2);
  }
  for (int k = 1; k <= NSQ; ++k) {
    const bool odd = (k % 2 == 1);
    float* cur = odd ? Ma : Mb;
    float* nxt = odd ? Mb : Ma;
    _Float16* curH = odd ? MaH : MbH;
    _Float16* nxtH = odd ? MbH : MaH;
    GP gs[3];
    gs[0] = gp0();
    gs[0].M = 1024; gs[0].N = 1024; gs[0].K1 = 1024;
    gs[0].A1 = cur; gs[0].a1 = lin(1024);
    gs[0].Bh = curH; gs[0].ldbh = 1024;    // symmetric f16 shadow as B
    gs[0].C1 = nxt; gs[0].c1 = lin(1024);
    gs[0].C1h = nxtH; gs[0].ldh = 1024;
    gs[0].fin = P + (long)(k - 1) * 256;   // A *= sscale, alpha *= sscale
    gs[0].fout = P + (long)k * 256;
    int nb = 1;
    if (k <= 5) {
      if (odd) {           // Newton b-step: X' = 2X - X@Yn
        float* cx = (k == 1 || k == 5) ? Xa : Xb;
        float* nx = (k == 1 || k == 5) ? Xb : Xa;
        _Float16* nxH = (k == 1 || k == 5) ? XbH : XaH;
        GP h = mmh(cx, YnH, 512, nx, nxH, 512);
        h.alpha = -1.0f; h.E1 = cx; h.e1 = lin(512); h.beta = 2.0f;
        gs[nb++] = h;
      } else {             // Newton a-step: Yn = St @ X
        _Float16* cxH = (k == 2) ? XbH : XaH;
        gs[nb++] = mmh(St, cxH, 512, Yn, YnH, 512);
      }
    } else if (k == 6) {
      gs[nb++] = mmh(K11u, XbH, 512, nullptr, WH, 512);      // W~ = K11^T@SinvT
      gs[nb++] = mmh(St, K21uH, 512, nullptr, CtDtH, 1024);  // Ct~ (unscaled)
    } else if (k == 7) {
      gs[nb++] = mmh(St, WH, 512, AtU, ABstH, 1024);         // At~ + At~H
      gs[nb++] = mmh(K12u, XbH, 512, BtU, BtuH, 512);        // Bt~ + Bt~H
    } else {
      gs[nb++] = mmh(AtU, ABstH, 1024, APf(2), StackH, 1536);     // At~^2
      gs[nb++] = mmh(BtU, ABstH, 1024, nullptr, StackH + 512, 1536); // Bt~At~
    }
    launch64(gs, nb);
  }
  scalar_k<<<1, 256, 0, stream>>>(P, NSQ, lgam, sc);
  prep2_k<<<dim3(768, 4), dim3(32, 8), 0, stream>>>(Kr, sc, ABstH, StackH,
                                                    BtuH, CtDtH, APf(2));

  // Addressing constants (L=8, 256 chunks/batch)
  const Addr A_u8   = two(8, 1048576, 255, 4096);
  const Addr A_s8   = two(8, 1049088, 255, 4096);
  const Addr A_z    = two(8, 262144, 255, 512);
  const Addr A_srow = two(11, 1049088, 2047, 512);

  // ---- pass1 radix-2: 4 serial steps j=2,4,6,8 (contiguous u-pair)
  //   l_j = l_{j-2}@At^2 + u_{j-2}@BtAt + u_{j-1}@Bt ; B = [At2|BtAt|Bt] stack
  //   riders: s1: At^3,At^4 | s2: At^5..8 | s3: T1=Q^2 | s4: T2=Q^4
  for (int j = 2; j <= 8; j += 2) {
    GP gs[5];
    int nb = 0;
    GP m = gp0();
    m.M = 4096; m.N = 512;
    if (j == 2) {
      m.K1 = 1024; m.A1 = u; m.a1 = A_u8;        // u rows 8c+0,8c+1 contiguous
      m.Bh = StackH + 512; m.ldbh = 1536;        // rows [BtAt; Bt]
    } else {
      m.K1 = 512; m.A1 = states + (long)(j - 2) * 512; m.a1 = A_s8;
      m.K2 = 1024; m.A2 = u + (long)(j - 2) * 512; m.a2 = A_u8;
      m.Bh = StackH; m.ldbh = 1536;              // rows [At2; BtAt; Bt]
    }
    if (j == 8) { m.C1 = Za + 512; m.c1 = A_z; }
    else { m.C1 = states + (long)j * 512; m.c1 = A_s8; }
    gs[nb++] = m;
    if (j == 2) {
      gs[nb++] = mmh(APf(2), ABstH, 1024, APf(3), APH_ + 0, 512);       // At^3
      gs[nb++] = mmh(APf(2), StackH, 1536, APf(4), APH_ + 262144, 512); // At^4
    } else if (j == 4) {
      for (int i = 1; i <= 4; ++i)
        gs[nb++] = mmh(APf(4), APHp(i), APHl(i), APf(4 + i),
                       APH_ + (long)(i + 1) * 262144, 512);             // At^5..8
    } else if (j == 6) {
      gs[nb++] = mmh(Tmf(0), TmH(0), 512, Tmf(1), TmH(1), 512);        // T1
    } else {
      gs[nb++] = mmh(Tmf(1), TmH(1), 512, Tmf(2), TmH(2), 512);        // T2
    }
    launch64(gs, nb);
  }

  // ---- Truncated Kogge-Stone (3 rounds, window 8): ||Q||<=0.2 =>
  //      truncation error <= ||Q^8||*||Y|| ~ 1e-5, far below threshold.
  //      odd-fill rides round 0; carry-copy folded in ----
  for (int k = 0; k <= 2; ++k) {
    const int s = 1 << k;
    float* Zs = (k % 2 == 0) ? Za : Zb;
    float* Zd = (k % 2 == 0) ? Zb : Za;
    GP gs[7];
    int nb = 0;
    GP m = gp0();
    m.M = 4096; m.N = 512; m.K1 = 512;
    m.A1 = Zs; m.a1 = A_z;
    m.Bh = TmH(k); m.ldbh = 512;
    m.E1 = Zs + (long)s * 512; m.e1 = A_z; m.beta = 1.0f;
    m.C1 = Zd + (long)s * 512; m.c1 = A_z;
    gs[nb++] = m;
    const Addr lowA = two(k, 262144, s - 1, 512);
    gs[nb++] = cpGP(Zs, lowA, Zd, lowA, 16 * s);
    if (k == 0) {
      // odd locals: l_1 = u_0@Bt; l_j = l_{j-1}@At + u_{j-1}@Bt (j=3,5,7)
      for (int j = 1; j <= 7; j += 2) {
        GP g = gp0();
        g.M = 4096; g.N = 512;
        if (j == 1) {
          g.K1 = 512; g.A1 = u; g.a1 = A_u8;
          g.Bh = ABstH + 512; g.ldbh = 1024;     // Bt only
        } else {
          g.K1 = 512; g.A1 = states + (long)(j - 1) * 512; g.a1 = A_s8;
          g.K2 = 512; g.A2 = u + (long)(j - 1) * 512; g.a2 = A_u8;
          g.Bh = ABstH; g.ldbh = 1024;           // [At; Bt]
        }
        g.C1 = states + (long)j * 512; g.c1 = A_s8;
        gs[nb++] = g;
      }
    }
    launch64(gs, nb);
  }
  float* Zf = Zb;   // rounds 0,1,2 end in Zb

  // ---- corrections + states-extreme copies (one dispatch) ----
  {
    GP gs[9];
    for (int j = 1; j <= 7; ++j) {
      GP g = gp0();
      g.M = 4096; g.N = 512; g.K1 = 512;
      g.A1 = Zf; g.a1 = A_z;
      g.Bh = APHp(j); g.ldbh = APHl(j);
      g.C2 = states + (long)j * 512; g.c2 = A_s8;
      g.E2 = states + (long)j * 512; g.e2 = A_s8;
      gs[j - 1] = g;
    }
    gs[7] = cpGP(Zf, A_z, states, A_s8, 4096);
    gs[8] = cpGP(Zf + (long)256 * 512, lin(262144),
                 states + (long)2048 * 512, lin(1049088), 16);
    launch128(gs, 9);
  }

  // ---- output = states[:, :T] @ Ct + u @ Dt ----
  {
    GP g = gp0();
    g.M = 32768; g.N = 512;
    g.K1 = 512; g.A1 = states; g.a1 = A_srow;
    g.K2 = 512; g.A2 = u; g.a2 = lin(512);
    g.Bh = CtDtH; g.ldbh = 1024;
    g.C1 = outp; g.c1 = lin(512);
    launch128(&g, 1);
  }
}